// Round 2
// baseline (465.593 us; speedup 1.0000x reference)
//
#include <hip/hip_runtime.h>

// RelationExtraction forward: 2x conv1d(D=768,W=3)+relu+residual -> span-max
// gather -> 2x linear+relu -> rel logits. All GEMMs via bf16 MFMA 16x16x32,
// fp32 accum, m97-style 128x128 tile with global_load_lds staging.

#define B_  32
#define D_  768
#define L_  512
#define LP_ 514          // L + 2 zero-pad rows per batch
#define H_  1024
#define R_  20
#define P_  4096
#define K1_ 2304         // 3*D, conv implicit-GEMM K

typedef __attribute__((ext_vector_type(8))) short sh8;
typedef __attribute__((ext_vector_type(4))) float f32x4;

__device__ __forceinline__ float bf2f(unsigned short u) {
  union { unsigned u; float f; } c; c.u = ((unsigned)u) << 16; return c.f;
}
__device__ __forceinline__ unsigned short f2bf(float f) {
  union { float f; unsigned u; } c; c.f = f;
  unsigned u = c.u + 0x7fffu + ((c.u >> 16) & 1u);   // RNE
  return (unsigned short)(u >> 16);
}
__device__ __forceinline__ void gld16(const void* g, void* l) {
  __builtin_amdgcn_global_load_lds((const __attribute__((address_space(1))) void*)g,
                                   (__attribute__((address_space(3))) void*)l,
                                   16, 0, 0);
}

// ---------------- transpose (B,D,L) f32 -> xpad (B,LP,D) bf16 interior ------
__global__ void transpose_pad_kernel(const float* __restrict__ x,
                                     unsigned short* __restrict__ xpad) {
  __shared__ float tile[32][33];
  const int b = blockIdx.z;
  const int l0 = blockIdx.x * 32, d0 = blockIdx.y * 32;
  const int tx = threadIdx.x, ty = threadIdx.y;   // 32 x 8
#pragma unroll
  for (int r = 0; r < 4; ++r)
    tile[ty + r * 8][tx] = x[((size_t)b * D_ + d0 + ty + r * 8) * L_ + l0 + tx];
  __syncthreads();
#pragma unroll
  for (int r = 0; r < 4; ++r) {
    int l = l0 + ty + r * 8, d = d0 + tx;
    xpad[((size_t)b * LP_ + 1 + l) * D_ + d] = f2bf(tile[tx][ty + r * 8]);
  }
}

// ---------------- zero the pad rows (j=0 and j=LP-1) of both pad buffers ----
__global__ void zero_pad_kernel(unsigned short* __restrict__ xp0,
                                unsigned short* __restrict__ xp1) {
  int i = blockIdx.x * 256 + threadIdx.x;          // i < B_*D_
  int b = i / D_, d = i % D_;
  size_t r0 = (size_t)b * LP_ * D_ + d;
  size_t r1 = ((size_t)b * LP_ + (LP_ - 1)) * D_ + d;
  xp0[r0] = 0; xp0[r1] = 0; xp1[r0] = 0; xp1[r1] = 0;
}

// ---------------- weight prep: conv (O,I,W)->(O,W,I) bf16; linears -> bf16 --
__global__ void prep_w_kernel(const float* __restrict__ w1, const float* __restrict__ w2,
                              const float* __restrict__ l1, const float* __restrict__ l2,
                              unsigned short* __restrict__ wt1, unsigned short* __restrict__ wt2,
                              unsigned short* __restrict__ l1b, unsigned short* __restrict__ l2b) {
  int i = blockIdx.x * 256 + threadIdx.x;
  const int CW = D_ * D_ * 3;                       // 1769472
  if (i < CW) {
    int o = i / (3 * D_), rem = i % (3 * D_);
    int k = rem / D_, c = rem % D_;
    int src = (o * D_ + c) * 3 + k;
    wt1[i] = f2bf(w1[src]);
    wt2[i] = f2bf(w2[src]);
  }
  if (i < H_ * D_) l1b[i] = f2bf(l1[i]);
  if (i < H_ * H_) l2b[i] = f2bf(l2[i]);
}

// ---------------- GEMM: C[m,n] = act(sum_k A[m,k]*Bw[n,k] + bias[n]) (+res) -
// APAD: A rows live in a (B,LP,D) padded buffer (conv implicit GEMM, lda=D_).
// RESIDUAL: add bf16 residual read from padded buffer row (b*LP+l+1).
// OUTPAD: write output to padded buffer row (b*LP+l+1), else row m.
template<bool APAD, bool RESIDUAL, bool OUTPAD>
__global__ __launch_bounds__(256)
void gemm_kernel(const unsigned short* __restrict__ A, int lda,
                 const unsigned short* __restrict__ Bw, int K,
                 const float* __restrict__ bias,
                 const unsigned short* __restrict__ res,
                 unsigned short* __restrict__ outb, int ldo) {
  __shared__ unsigned short Atile[128 * 32];
  __shared__ unsigned short Btile[128 * 32];

  const int tid  = threadIdx.x;
  const int wave = tid >> 6;
  const int lane = tid & 63;
  const int wr = wave >> 1, wc = wave & 1;          // 2x2 waves -> 64x64 each
  const int m0 = blockIdx.y * 128;
  const int n0 = blockIdx.x * 128;

  int arow0;
  if (APAD) arow0 = (m0 >> 9) * LP_ + (m0 & 511);   // tile fully inside batch
  else      arow0 = m0;

  f32x4 acc[4][4];
#pragma unroll
  for (int i = 0; i < 4; ++i)
#pragma unroll
    for (int j = 0; j < 4; ++j) acc[i][j] = (f32x4)(0.0f);

  const int srow = lane >> 2;                       // 0..15 row within chunk
  const int scol = (lane & 3) * 8;                  // 8-elem col offset
  const int l16 = lane & 15, lq = lane >> 4;

  const unsigned short* Ab = A + (size_t)arow0 * lda + scol;
  const unsigned short* Bb = Bw + (size_t)n0 * K + scol;

  for (int kk = 0; kk < K; kk += 32) {
#pragma unroll
    for (int c2 = 0; c2 < 2; ++c2) {
      int c = wave * 2 + c2;                        // LDS chunk (16 rows = 1KB)
      int row = c * 16 + srow;
      gld16(Ab + (size_t)row * lda + kk, &Atile[c * 512]);
      gld16(Bb + (size_t)row * K   + kk, &Btile[c * 512]);
    }
    __syncthreads();
    sh8 af[4], bfr[4];
#pragma unroll
    for (int i = 0; i < 4; ++i)
      af[i] = *(const sh8*)&Atile[(wr * 64 + i * 16 + l16) * 32 + lq * 8];
#pragma unroll
    for (int j = 0; j < 4; ++j)
      bfr[j] = *(const sh8*)&Btile[(wc * 64 + j * 16 + l16) * 32 + lq * 8];
#pragma unroll
    for (int i = 0; i < 4; ++i)
#pragma unroll
      for (int j = 0; j < 4; ++j)
        acc[i][j] = __builtin_amdgcn_mfma_f32_16x16x32_bf16(af[i], bfr[j], acc[i][j], 0, 0, 0);
    __syncthreads();
  }

#pragma unroll
  for (int i = 0; i < 4; ++i) {
#pragma unroll
    for (int j = 0; j < 4; ++j) {
      int col = n0 + wc * 64 + j * 16 + l16;
      float bn = bias[col];
#pragma unroll
      for (int r = 0; r < 4; ++r) {
        int m = m0 + wr * 64 + i * 16 + lq * 4 + r;
        float v = acc[i][j][r] + bn;
        v = fmaxf(v, 0.0f);                          // relu before residual
        size_t orow = (size_t)m;
        if (OUTPAD || RESIDUAL) {
          int bb = m >> 9, ll = m & 511;
          size_t prow = (size_t)bb * LP_ + ll + 1;
          if (RESIDUAL) v += bf2f(res[prow * D_ + col]);
          if (OUTPAD) orow = prow;
        }
        outb[orow * (size_t)ldo + col] = f2bf(v);
      }
    }
  }
}

// ---------------- span max gather: maxed[p,:] = max(head) + max(tail) -------
__global__ void span_kernel(const unsigned short* __restrict__ x2,
                            const int* __restrict__ pb, const int* __restrict__ hi,
                            const int* __restrict__ hs, const int* __restrict__ ti,
                            const int* __restrict__ ts,
                            unsigned short* __restrict__ maxed) {
  const int p = blockIdx.x, t = threadIdx.x;        // 256 thr, 3 cols each
  const int b = pb[p];
  const unsigned short* xb = x2 + (size_t)b * L_ * D_;

  float mh0 = -1e30f, mh1 = -1e30f, mh2 = -1e30f;
  {
    int idx = hi[p], sp = hs[p];
    for (int s = 0; s < sp; ++s) {
      int pos = idx + s; if (pos > L_ - 1) pos = L_ - 1;
      const unsigned short* rp = xb + (size_t)pos * D_;
      mh0 = fmaxf(mh0, bf2f(rp[t]));
      mh1 = fmaxf(mh1, bf2f(rp[t + 256]));
      mh2 = fmaxf(mh2, bf2f(rp[t + 512]));
    }
  }
  float mt0 = -1e30f, mt1 = -1e30f, mt2 = -1e30f;
  {
    int idx = ti[p], sp = ts[p];
    for (int s = 0; s < sp; ++s) {
      int pos = idx + s; if (pos > L_ - 1) pos = L_ - 1;
      const unsigned short* rp = xb + (size_t)pos * D_;
      mt0 = fmaxf(mt0, bf2f(rp[t]));
      mt1 = fmaxf(mt1, bf2f(rp[t + 256]));
      mt2 = fmaxf(mt2, bf2f(rp[t + 512]));
    }
  }
  maxed[(size_t)p * D_ + t]       = f2bf(mh0 + mt0);
  maxed[(size_t)p * D_ + t + 256] = f2bf(mh1 + mt1);
  maxed[(size_t)p * D_ + t + 512] = f2bf(mh2 + mt2);
}

// ---------------- rel head: logits[p,r] = h2[p,:]·rel_w[r,:] + rel_b --------
__global__ void rel_kernel(const unsigned short* __restrict__ h2,
                           const float* __restrict__ rw, const float* __restrict__ rb,
                           const int* __restrict__ labels, float* __restrict__ out) {
  const int wave = threadIdx.x >> 6, lane = threadIdx.x & 63;
  const int p = blockIdx.x * 4 + wave;              // 1 wave per pair
  float a[16];
#pragma unroll
  for (int j = 0; j < 16; ++j) a[j] = bf2f(h2[(size_t)p * H_ + lane + j * 64]);
  for (int r = 0; r < R_; ++r) {
    float s = 0.f;
    const float* wrow = rw + (size_t)r * H_;
#pragma unroll
    for (int j = 0; j < 16; ++j) s += a[j] * wrow[lane + j * 64];
#pragma unroll
    for (int m = 32; m >= 1; m >>= 1) s += __shfl_xor(s, m);
    if (lane == 0) out[(size_t)p * R_ + r] = s + rb[r];
  }
  if (threadIdx.x < 4) {
    int pp = blockIdx.x * 4 + threadIdx.x;
    out[(size_t)P_ * R_ + pp] = (float)labels[pp];
  }
}

extern "C" void kernel_launch(void* const* d_in, const int* in_sizes, int n_in,
                              void* d_out, int out_size, void* d_ws, size_t ws_size,
                              hipStream_t stream) {
  const float* x      = (const float*)d_in[0];
  const int*   pb     = (const int*)d_in[1];
  const int*   hi     = (const int*)d_in[2];
  const int*   hs     = (const int*)d_in[3];
  const int*   ti     = (const int*)d_in[4];
  const int*   ts     = (const int*)d_in[5];
  const int*   labels = (const int*)d_in[6];
  const float* w1     = (const float*)d_in[7];
  const float* b1     = (const float*)d_in[8];
  const float* w2     = (const float*)d_in[9];
  const float* b2     = (const float*)d_in[10];
  const float* l1w    = (const float*)d_in[11];
  const float* l1bias = (const float*)d_in[12];
  const float* l2w    = (const float*)d_in[13];
  const float* l2bias = (const float*)d_in[14];
  const float* rw     = (const float*)d_in[15];
  const float* rbias  = (const float*)d_in[16];
  float* out = (float*)d_out;

  unsigned short* ws    = (unsigned short*)d_ws;
  unsigned short* xpad0 = ws;                                   // B*LP*D
  unsigned short* xpad1 = xpad0 + (size_t)B_ * LP_ * D_;        // B*LP*D
  unsigned short* x2    = xpad1 + (size_t)B_ * LP_ * D_;        // B*L*D
  unsigned short* wt1   = x2    + (size_t)B_ * L_ * D_;         // D*3*D
  unsigned short* wt2   = wt1   + (size_t)D_ * 3 * D_;
  unsigned short* l1b   = wt2   + (size_t)D_ * 3 * D_;          // H*D
  unsigned short* l2b   = l1b   + (size_t)H_ * D_;              // H*H
  // xpad0 is dead after conv GEMM1 -> reuse for maxed/h1/h2 (11.5M <= 12.6M elems)
  unsigned short* maxed = xpad0;                                // P*D
  unsigned short* h1    = xpad0 + (size_t)P_ * D_;              // P*H
  unsigned short* h2    = h1    + (size_t)P_ * H_;              // P*H

  transpose_pad_kernel<<<dim3(L_ / 32, D_ / 32, B_), dim3(32, 8, 1), 0, stream>>>(x, xpad0);
  zero_pad_kernel<<<(B_ * D_) / 256, 256, 0, stream>>>(xpad0, xpad1);
  prep_w_kernel<<<(D_ * D_ * 3) / 256, 256, 0, stream>>>(w1, w2, l1w, l2w, wt1, wt2, l1b, l2b);

  // conv1: relu(conv(x)+b1) + x -> xpad1 (padded bf16)
  gemm_kernel<true, true, true><<<dim3(D_ / 128, (B_ * L_) / 128), 256, 0, stream>>>(
      xpad0, D_, wt1, K1_, b1, xpad0, xpad1, D_);
  // conv2: relu(conv(x1)+b2) + x1 -> x2 (non-padded bf16)
  gemm_kernel<true, true, false><<<dim3(D_ / 128, (B_ * L_) / 128), 256, 0, stream>>>(
      xpad1, D_, wt2, K1_, b2, xpad1, x2, D_);

  span_kernel<<<P_, 256, 0, stream>>>(x2, pb, hi, hs, ti, ts, maxed);

  // lin1: relu(maxed @ l1w^T + b) -> h1
  gemm_kernel<false, false, false><<<dim3(H_ / 128, P_ / 128), 256, 0, stream>>>(
      maxed, D_, l1b, D_, l1bias, nullptr, h1, H_);
  // lin2: relu(h1 @ l2w^T + b) -> h2
  gemm_kernel<false, false, false><<<dim3(H_ / 128, P_ / 128), 256, 0, stream>>>(
      h1, H_, l2b, H_, l2bias, nullptr, h2, H_);

  rel_kernel<<<P_ / 4, 256, 0, stream>>>(h2, rw, rbias, labels, out);
}

// Round 3
// 414.929 us; speedup vs baseline: 1.1221x; 1.1221x over previous
//
#include <hip/hip_runtime.h>

// RelationExtraction forward: 2x conv1d(D=768,W=3)+relu+residual -> span-max
// gather -> 2x linear+relu -> rel logits. GEMMs: bf16 MFMA 16x16x32, fp32
// accum, 128x128 tile, double-buffered global_load_lds prefetch (T3-minimum),
// bijective XCD-chunked block swizzle (T1).

#define B_  32
#define D_  768
#define L_  512
#define LP_ 514          // L + 2 zero-pad rows per batch
#define H_  1024
#define R_  20
#define P_  4096
#define K1_ 2304         // 3*D, conv implicit-GEMM K

typedef __attribute__((ext_vector_type(8))) short sh8;
typedef __attribute__((ext_vector_type(4))) short sh4;
typedef __attribute__((ext_vector_type(4))) float f32x4;

__device__ __forceinline__ float bf2f(unsigned short u) {
  union { unsigned u; float f; } c; c.u = ((unsigned)u) << 16; return c.f;
}
__device__ __forceinline__ unsigned short f2bf(float f) {
  union { float f; unsigned u; } c; c.f = f;
  unsigned u = c.u + 0x7fffu + ((c.u >> 16) & 1u);   // RNE
  return (unsigned short)(u >> 16);
}
__device__ __forceinline__ void gld16(const void* g, void* l) {
  __builtin_amdgcn_global_load_lds((const __attribute__((address_space(1))) void*)g,
                                   (__attribute__((address_space(3))) void*)l,
                                   16, 0, 0);
}

// ---------------- transpose (B,D,L) f32 -> xpad (B,LP,D) bf16 interior ------
__global__ void transpose_pad_kernel(const float* __restrict__ x,
                                     unsigned short* __restrict__ xpad) {
  __shared__ float tile[32][33];
  const int b = blockIdx.z;
  const int l0 = blockIdx.x * 32, d0 = blockIdx.y * 32;
  const int tx = threadIdx.x, ty = threadIdx.y;   // 32 x 8
#pragma unroll
  for (int r = 0; r < 4; ++r)
    tile[ty + r * 8][tx] = x[((size_t)b * D_ + d0 + ty + r * 8) * L_ + l0 + tx];
  __syncthreads();
#pragma unroll
  for (int r = 0; r < 4; ++r) {
    int l = l0 + ty + r * 8, d = d0 + tx;
    xpad[((size_t)b * LP_ + 1 + l) * D_ + d] = f2bf(tile[tx][ty + r * 8]);
  }
}

// ---------------- zero the pad rows (j=0 and j=LP-1) of both pad buffers ----
__global__ void zero_pad_kernel(unsigned short* __restrict__ xp0,
                                unsigned short* __restrict__ xp1) {
  int i = blockIdx.x * 256 + threadIdx.x;          // i < B_*D_
  int b = i / D_, d = i % D_;
  size_t r0 = (size_t)b * LP_ * D_ + d;
  size_t r1 = ((size_t)b * LP_ + (LP_ - 1)) * D_ + d;
  xp0[r0] = 0; xp0[r1] = 0; xp1[r0] = 0; xp1[r1] = 0;
}

// ---------------- weight prep: conv (O,I,W)->(O,W,I) bf16; linears -> bf16 --
__global__ void prep_w_kernel(const float* __restrict__ w1, const float* __restrict__ w2,
                              const float* __restrict__ l1, const float* __restrict__ l2,
                              unsigned short* __restrict__ wt1, unsigned short* __restrict__ wt2,
                              unsigned short* __restrict__ l1b, unsigned short* __restrict__ l2b) {
  int i = blockIdx.x * 256 + threadIdx.x;
  const int CW = D_ * D_ * 3;                       // 1769472
  if (i < CW) {
    int o = i / (3 * D_), rem = i % (3 * D_);
    int k = rem / D_, c = rem % D_;
    int src = (o * D_ + c) * 3 + k;
    wt1[i] = f2bf(w1[src]);
    wt2[i] = f2bf(w2[src]);
  }
  if (i < H_ * D_) l1b[i] = f2bf(l1[i]);
  if (i < H_ * H_) l2b[i] = f2bf(l2[i]);
}

// ---------------- GEMM: C[m,n] = act(sum_k A[m,k]*Bw[n,k] + bias[n]) (+res) -
// APAD: A rows live in a (B,LP,D) padded buffer (conv implicit GEMM, lda=D_).
// RESIDUAL: add bf16 residual read from padded buffer row (b*LP+l+1).
// OUTPAD: write output to padded buffer row (b*LP+l+1), else row m.
// T1: bijective XCD-chunked swizzle -> blocks sharing weights/A colocate per XCD.
// T3-minimum: double-buffered LDS, prefetch next K-step before MFMA, 1 barrier/iter.
template<bool APAD, bool RESIDUAL, bool OUTPAD>
__global__ __launch_bounds__(256)
void gemm_kernel(const unsigned short* __restrict__ A, int lda,
                 const unsigned short* __restrict__ Bw, int K,
                 const float* __restrict__ bias,
                 const unsigned short* __restrict__ res,
                 unsigned short* __restrict__ outb, int ldo) {
  __shared__ unsigned short Atile[2][128 * 32];
  __shared__ unsigned short Btile[2][128 * 32];

  const int tid  = threadIdx.x;
  const int wave = tid >> 6;
  const int lane = tid & 63;
  const int wr = wave >> 1, wc = wave & 1;          // 2x2 waves -> 64x64 each

  // XCD-chunked bijective swizzle (nwg % 8 == 0 for all our grids)
  const int nwg  = gridDim.x * gridDim.y;
  const int orig = blockIdx.y * gridDim.x + blockIdx.x;
  int bswz = orig;
  if ((nwg & 7) == 0) bswz = (orig & 7) * (nwg >> 3) + (orig >> 3);
  const int m0 = (bswz / gridDim.x) * 128;
  const int n0 = (bswz % gridDim.x) * 128;

  int arow0;
  if (APAD) arow0 = (m0 >> 9) * LP_ + (m0 & 511);   // tile fully inside batch
  else      arow0 = m0;

  f32x4 acc[4][4];
#pragma unroll
  for (int i = 0; i < 4; ++i)
#pragma unroll
    for (int j = 0; j < 4; ++j) acc[i][j] = (f32x4)(0.0f);

  const int srow = lane >> 2;                       // 0..15 row within chunk
  const int scol = (lane & 3) * 8;                  // 8-elem col offset
  const int l16 = lane & 15, lq = lane >> 4;

  const unsigned short* Ab = A + (size_t)arow0 * lda + scol;
  const unsigned short* Bb = Bw + (size_t)n0 * K + scol;
  const int c0 = wave * 2, c1 = wave * 2 + 1;       // this wave's LDS chunks
  const int rowA0 = c0 * 16 + srow, rowA1 = c1 * 16 + srow;

  // prologue: stage K-step 0 into buffer 0
  gld16(Ab + (size_t)rowA0 * lda, &Atile[0][c0 * 512]);
  gld16(Bb + (size_t)rowA0 * K,   &Btile[0][c0 * 512]);
  gld16(Ab + (size_t)rowA1 * lda, &Atile[0][c1 * 512]);
  gld16(Bb + (size_t)rowA1 * K,   &Btile[0][c1 * 512]);
  __syncthreads();                                   // drains vmcnt(0)

  int cur = 0;
  for (int kk = 0; kk < K; kk += 32) {
    if (kk + 32 < K) {                               // prefetch next K-step
      int kn = kk + 32, nb = cur ^ 1;
      gld16(Ab + (size_t)rowA0 * lda + kn, &Atile[nb][c0 * 512]);
      gld16(Bb + (size_t)rowA0 * K   + kn, &Btile[nb][c0 * 512]);
      gld16(Ab + (size_t)rowA1 * lda + kn, &Atile[nb][c1 * 512]);
      gld16(Bb + (size_t)rowA1 * K   + kn, &Btile[nb][c1 * 512]);
    }
    sh8 af[4], bfr[4];
#pragma unroll
    for (int i = 0; i < 4; ++i)
      af[i] = *(const sh8*)&Atile[cur][(wr * 64 + i * 16 + l16) * 32 + lq * 8];
#pragma unroll
    for (int j = 0; j < 4; ++j)
      bfr[j] = *(const sh8*)&Btile[cur][(wc * 64 + j * 16 + l16) * 32 + lq * 8];
#pragma unroll
    for (int i = 0; i < 4; ++i)
#pragma unroll
      for (int j = 0; j < 4; ++j)
        acc[i][j] = __builtin_amdgcn_mfma_f32_16x16x32_bf16(af[i], bfr[j], acc[i][j], 0, 0, 0);
    __syncthreads();                                 // drains vmcnt+lgkm; swap safe
    cur ^= 1;
  }

#pragma unroll
  for (int i = 0; i < 4; ++i) {
#pragma unroll
    for (int j = 0; j < 4; ++j) {
      int col = n0 + wc * 64 + j * 16 + l16;
      float bn = bias[col];
#pragma unroll
      for (int r = 0; r < 4; ++r) {
        int m = m0 + wr * 64 + i * 16 + lq * 4 + r;
        float v = acc[i][j][r] + bn;
        v = fmaxf(v, 0.0f);                          // relu before residual
        size_t orow = (size_t)m;
        if (OUTPAD || RESIDUAL) {
          int bb = m >> 9, ll = m & 511;
          size_t prow = (size_t)bb * LP_ + ll + 1;
          if (RESIDUAL) v += bf2f(res[prow * D_ + col]);
          if (OUTPAD) orow = prow;
        }
        outb[orow * (size_t)ldo + col] = f2bf(v);
      }
    }
  }
}

// ---------------- span max gather: maxed[p,:] = max(head) + max(tail) -------
// 192 threads x short4: 8 B/lane, 1536 B contiguous per row read.
__global__ void span_kernel(const unsigned short* __restrict__ x2,
                            const int* __restrict__ pb, const int* __restrict__ hi,
                            const int* __restrict__ hs, const int* __restrict__ ti,
                            const int* __restrict__ ts,
                            unsigned short* __restrict__ maxed) {
  const int p = blockIdx.x, t = threadIdx.x;        // 192 threads, 4 cols each
  const int b = pb[p];
  const unsigned short* xb = x2 + (size_t)b * L_ * D_ + t * 4;

  float mh[4], mt[4];
#pragma unroll
  for (int j = 0; j < 4; ++j) { mh[j] = -1e30f; mt[j] = -1e30f; }
  {
    int idx = hi[p], sp = hs[p];
    for (int s = 0; s < sp; ++s) {
      int pos = idx + s; if (pos > L_ - 1) pos = L_ - 1;
      sh4 v = *(const sh4*)(xb + (size_t)pos * D_);
#pragma unroll
      for (int j = 0; j < 4; ++j) mh[j] = fmaxf(mh[j], bf2f((unsigned short)v[j]));
    }
  }
  {
    int idx = ti[p], sp = ts[p];
    for (int s = 0; s < sp; ++s) {
      int pos = idx + s; if (pos > L_ - 1) pos = L_ - 1;
      sh4 v = *(const sh4*)(xb + (size_t)pos * D_);
#pragma unroll
      for (int j = 0; j < 4; ++j) mt[j] = fmaxf(mt[j], bf2f((unsigned short)v[j]));
    }
  }
  sh4 o;
#pragma unroll
  for (int j = 0; j < 4; ++j) o[j] = (short)f2bf(mh[j] + mt[j]);
  *(sh4*)(maxed + (size_t)p * D_ + t * 4) = o;
}

// ---------------- rel head: logits[p,r] = h2[p,:]·rel_w[r,:] + rel_b --------
__global__ void rel_kernel(const unsigned short* __restrict__ h2,
                           const float* __restrict__ rw, const float* __restrict__ rb,
                           const int* __restrict__ labels, float* __restrict__ out) {
  const int wave = threadIdx.x >> 6, lane = threadIdx.x & 63;
  const int p = blockIdx.x * 4 + wave;              // 1 wave per pair
  float a[16];
#pragma unroll
  for (int j = 0; j < 16; ++j) a[j] = bf2f(h2[(size_t)p * H_ + lane + j * 64]);
  for (int r = 0; r < R_; ++r) {
    float s = 0.f;
    const float* wrow = rw + (size_t)r * H_;
#pragma unroll
    for (int j = 0; j < 16; ++j) s += a[j] * wrow[lane + j * 64];
#pragma unroll
    for (int m = 32; m >= 1; m >>= 1) s += __shfl_xor(s, m);
    if (lane == 0) out[(size_t)p * R_ + r] = s + rb[r];
  }
  if (threadIdx.x < 4) {
    int pp = blockIdx.x * 4 + threadIdx.x;
    out[(size_t)P_ * R_ + pp] = (float)labels[pp];
  }
}

extern "C" void kernel_launch(void* const* d_in, const int* in_sizes, int n_in,
                              void* d_out, int out_size, void* d_ws, size_t ws_size,
                              hipStream_t stream) {
  const float* x      = (const float*)d_in[0];
  const int*   pb     = (const int*)d_in[1];
  const int*   hi     = (const int*)d_in[2];
  const int*   hs     = (const int*)d_in[3];
  const int*   ti     = (const int*)d_in[4];
  const int*   ts     = (const int*)d_in[5];
  const int*   labels = (const int*)d_in[6];
  const float* w1     = (const float*)d_in[7];
  const float* b1     = (const float*)d_in[8];
  const float* w2     = (const float*)d_in[9];
  const float* b2     = (const float*)d_in[10];
  const float* l1w    = (const float*)d_in[11];
  const float* l1bias = (const float*)d_in[12];
  const float* l2w    = (const float*)d_in[13];
  const float* l2bias = (const float*)d_in[14];
  const float* rw     = (const float*)d_in[15];
  const float* rbias  = (const float*)d_in[16];
  float* out = (float*)d_out;

  unsigned short* ws    = (unsigned short*)d_ws;
  unsigned short* xpad0 = ws;                                   // B*LP*D
  unsigned short* xpad1 = xpad0 + (size_t)B_ * LP_ * D_;        // B*LP*D
  unsigned short* x2    = xpad1 + (size_t)B_ * LP_ * D_;        // B*L*D
  unsigned short* wt1   = x2    + (size_t)B_ * L_ * D_;         // D*3*D
  unsigned short* wt2   = wt1   + (size_t)D_ * 3 * D_;
  unsigned short* l1b   = wt2   + (size_t)D_ * 3 * D_;          // H*D
  unsigned short* l2b   = l1b   + (size_t)H_ * D_;              // H*H
  // xpad0 is dead after conv GEMM1 -> reuse for maxed/h1/h2 (11.5M <= 12.6M elems)
  unsigned short* maxed = xpad0;                                // P*D
  unsigned short* h1    = xpad0 + (size_t)P_ * D_;              // P*H
  unsigned short* h2    = h1    + (size_t)P_ * H_;              // P*H

  transpose_pad_kernel<<<dim3(L_ / 32, D_ / 32, B_), dim3(32, 8, 1), 0, stream>>>(x, xpad0);
  zero_pad_kernel<<<(B_ * D_) / 256, 256, 0, stream>>>(xpad0, xpad1);
  prep_w_kernel<<<(D_ * D_ * 3) / 256, 256, 0, stream>>>(w1, w2, l1w, l2w, wt1, wt2, l1b, l2b);

  // conv1: relu(conv(x)+b1) + x -> xpad1 (padded bf16)
  gemm_kernel<true, true, true><<<dim3(D_ / 128, (B_ * L_) / 128), 256, 0, stream>>>(
      xpad0, D_, wt1, K1_, b1, xpad0, xpad1, D_);
  // conv2: relu(conv(x1)+b2) + x1 -> x2 (non-padded bf16)
  gemm_kernel<true, true, false><<<dim3(D_ / 128, (B_ * L_) / 128), 256, 0, stream>>>(
      xpad1, D_, wt2, K1_, b2, xpad1, x2, D_);

  span_kernel<<<P_, 192, 0, stream>>>(x2, pb, hi, hs, ti, ts, maxed);

  // lin1: relu(maxed @ l1w^T + b) -> h1
  gemm_kernel<false, false, false><<<dim3(H_ / 128, P_ / 128), 256, 0, stream>>>(
      maxed, D_, l1b, D_, l1bias, nullptr, h1, H_);
  // lin2: relu(h1 @ l2w^T + b) -> h2
  gemm_kernel<false, false, false><<<dim3(H_ / 128, P_ / 128), 256, 0, stream>>>(
      h1, H_, l2b, H_, l2bias, nullptr, h2, H_);

  rel_kernel<<<P_ / 4, 256, 0, stream>>>(h2, rw, rbias, labels, out);
}

// Round 5
// 365.996 us; speedup vs baseline: 1.2721x; 1.1337x over previous
//
#include <hip/hip_runtime.h>

// RelationExtraction forward: 2x conv1d(D=768,W=3)+relu+residual -> span-max
// gather -> 2x linear+relu -> rel logits. GEMMs: bf16 MFMA 16x16x32, fp32
// accum, 128x128 tile, 3-buffer LDS pipeline with counted vmcnt (T3+T4),
// bijective XCD-chunked block swizzle (T1).

#define B_  32
#define D_  768
#define L_  512
#define LP_ 514          // L + 2 zero-pad rows per batch
#define H_  1024
#define R_  20
#define P_  4096
#define K1_ 2304         // 3*D, conv implicit-GEMM K

typedef __attribute__((ext_vector_type(8))) short sh8;
typedef __attribute__((ext_vector_type(4))) short sh4;
typedef __attribute__((ext_vector_type(4))) float f32x4;

__device__ __forceinline__ float bf2f(unsigned short u) {
  union { unsigned u; float f; } c; c.u = ((unsigned)u) << 16; return c.f;
}
__device__ __forceinline__ unsigned short f2bf(float f) {
  union { float f; unsigned u; } c; c.f = f;
  unsigned u = c.u + 0x7fffu + ((c.u >> 16) & 1u);   // RNE
  return (unsigned short)(u >> 16);
}
__device__ __forceinline__ void gld16(const void* g, void* l) {
  __builtin_amdgcn_global_load_lds((const __attribute__((address_space(1))) void*)g,
                                   (__attribute__((address_space(3))) void*)l,
                                   16, 0, 0);
}

// ---------------- transpose (B,D,L) f32 -> xpad (B,LP,D) bf16 interior ------
__global__ void transpose_pad_kernel(const float* __restrict__ x,
                                     unsigned short* __restrict__ xpad) {
  __shared__ float tile[32][33];
  const int b = blockIdx.z;
  const int l0 = blockIdx.x * 32, d0 = blockIdx.y * 32;
  const int tx = threadIdx.x, ty = threadIdx.y;   // 32 x 8
#pragma unroll
  for (int r = 0; r < 4; ++r)
    tile[ty + r * 8][tx] = x[((size_t)b * D_ + d0 + ty + r * 8) * L_ + l0 + tx];
  __syncthreads();
#pragma unroll
  for (int r = 0; r < 4; ++r) {
    int l = l0 + ty + r * 8, d = d0 + tx;
    xpad[((size_t)b * LP_ + 1 + l) * D_ + d] = f2bf(tile[tx][ty + r * 8]);
  }
}

// ---------------- zero the pad rows (j=0 and j=LP-1) of both pad buffers ----
__global__ void zero_pad_kernel(unsigned short* __restrict__ xp0,
                                unsigned short* __restrict__ xp1) {
  int i = blockIdx.x * 256 + threadIdx.x;          // i < B_*D_
  int b = i / D_, d = i % D_;
  size_t r0 = (size_t)b * LP_ * D_ + d;
  size_t r1 = ((size_t)b * LP_ + (LP_ - 1)) * D_ + d;
  xp0[r0] = 0; xp0[r1] = 0; xp1[r0] = 0; xp1[r1] = 0;
}

// ---------------- weight prep: conv (O,I,W)->(O,W,I) bf16; linears -> bf16 --
__global__ void prep_w_kernel(const float* __restrict__ w1, const float* __restrict__ w2,
                              const float* __restrict__ l1, const float* __restrict__ l2,
                              unsigned short* __restrict__ wt1, unsigned short* __restrict__ wt2,
                              unsigned short* __restrict__ l1b, unsigned short* __restrict__ l2b) {
  int i = blockIdx.x * 256 + threadIdx.x;
  const int CW = D_ * D_ * 3;                       // 1769472
  if (i < CW) {
    int o = i / (3 * D_), rem = i % (3 * D_);
    int k = rem / D_, c = rem % D_;
    int src = (o * D_ + c) * 3 + k;
    wt1[i] = f2bf(w1[src]);
    wt2[i] = f2bf(w2[src]);
  }
  if (i < H_ * D_) l1b[i] = f2bf(l1[i]);
  if (i < H_ * H_) l2b[i] = f2bf(l2[i]);
}

// ---------------- GEMM: C[m,n] = act(sum_k A[m,k]*Bw[n,k] + bias[n]) (+res) -
// APAD: A rows live in a (B,LP,D) padded buffer (conv implicit GEMM, lda=D_).
// RESIDUAL: add bf16 residual read from padded buffer row (b*LP+l+1).
// OUTPAD: write output to padded buffer row (b*LP+l+1), else row m.
// T1: bijective XCD-chunked swizzle (all blocks of one XCD co-resident ->
//     weight panel stays live in that XCD's L2).
// T3+T4: 3-buffer LDS pipeline, loads issued 2 K-steps ahead, raw s_barrier
//     with counted s_waitcnt vmcnt(4) (vmcnt(0) only on the final iter).
//     Safety: at the top-of-iter barrier every wave has drained its previous
//     ds_reads (compiler emits lgkmcnt before MFMA), so staging into buffer
//     (t+2)%3 == (t-1)%3 after the barrier is race-free; per-wave vmcnt +
//     barrier => all waves' iter-t loads have landed before ds_read.
template<bool APAD, bool RESIDUAL, bool OUTPAD>
__global__ __launch_bounds__(256)
void gemm_kernel(const unsigned short* __restrict__ A, int lda,
                 const unsigned short* __restrict__ Bw, int K,
                 const float* __restrict__ bias,
                 const unsigned short* __restrict__ res,
                 unsigned short* __restrict__ outb, int ldo) {
  __shared__ unsigned short Atile[3][128 * 32];
  __shared__ unsigned short Btile[3][128 * 32];

  const int tid  = threadIdx.x;
  const int wave = tid >> 6;
  const int lane = tid & 63;
  const int wr = wave >> 1, wc = wave & 1;          // 2x2 waves -> 64x64 each

  // XCD-chunked bijective swizzle (nwg % 8 == 0 for all our grids)
  const int nwg  = gridDim.x * gridDim.y;
  const int orig = blockIdx.y * gridDim.x + blockIdx.x;
  int bswz = orig;
  if ((nwg & 7) == 0) bswz = (orig & 7) * (nwg >> 3) + (orig >> 3);
  const int m0 = (bswz / gridDim.x) * 128;
  const int n0 = (bswz % gridDim.x) * 128;

  int arow0;
  if (APAD) arow0 = (m0 >> 9) * LP_ + (m0 & 511);   // tile fully inside batch
  else      arow0 = m0;

  f32x4 acc[4][4];
#pragma unroll
  for (int i = 0; i < 4; ++i)
#pragma unroll
    for (int j = 0; j < 4; ++j) acc[i][j] = (f32x4)(0.0f);

  const int srow = lane >> 2;                       // 0..15 row within chunk
  const int scol = (lane & 3) * 8;                  // 8-elem col offset
  const int l16 = lane & 15, lq = lane >> 4;

  const unsigned short* Ab = A + (size_t)arow0 * lda + scol;
  const unsigned short* Bb = Bw + (size_t)n0 * K + scol;
  const int c0 = wave * 2, c1 = wave * 2 + 1;       // this wave's LDS chunks
  const int rowA0 = c0 * 16 + srow, rowA1 = c1 * 16 + srow;

#define STAGE(buf, kk) do {                                          \
    gld16(Ab + (size_t)rowA0 * lda + (kk), &Atile[buf][c0 * 512]);   \
    gld16(Bb + (size_t)rowA0 * K   + (kk), &Btile[buf][c0 * 512]);   \
    gld16(Ab + (size_t)rowA1 * lda + (kk), &Atile[buf][c1 * 512]);   \
    gld16(Bb + (size_t)rowA1 * K   + (kk), &Btile[buf][c1 * 512]);   \
  } while (0)

  const int nIter = K >> 5;                          // K/32, >= 3 for all uses
  STAGE(0, 0);                                       // 4 loads in flight
  STAGE(1, 32);                                      // 8 loads in flight

  int cur = 0;
  for (int t = 0; t < nIter; ++t) {
    // wait for own iter-t loads (4 newer ones may stay in flight), then sync
    if (t + 1 < nIter) asm volatile("s_waitcnt vmcnt(4)" ::: "memory");
    else               asm volatile("s_waitcnt vmcnt(0)" ::: "memory");
    __builtin_amdgcn_s_barrier();

    sh8 af[4], bfr[4];
#pragma unroll
    for (int i = 0; i < 4; ++i)
      af[i] = *(const sh8*)&Atile[cur][(wr * 64 + i * 16 + l16) * 32 + lq * 8];
#pragma unroll
    for (int j = 0; j < 4; ++j)
      bfr[j] = *(const sh8*)&Btile[cur][(wc * 64 + j * 16 + l16) * 32 + lq * 8];

    if (t + 2 < nIter) {                             // stage 2 steps ahead
      int sb = cur + 2; if (sb >= 3) sb -= 3;        // (t+2)%3
      STAGE(sb, (t + 2) * 32);
    }

#pragma unroll
    for (int i = 0; i < 4; ++i)
#pragma unroll
      for (int j = 0; j < 4; ++j)
        acc[i][j] = __builtin_amdgcn_mfma_f32_16x16x32_bf16(af[i], bfr[j], acc[i][j], 0, 0, 0);

    cur = (cur == 2) ? 0 : cur + 1;
  }
#undef STAGE

#pragma unroll
  for (int i = 0; i < 4; ++i) {
#pragma unroll
    for (int j = 0; j < 4; ++j) {
      int col = n0 + wc * 64 + j * 16 + l16;
      float bn = bias[col];
#pragma unroll
      for (int r = 0; r < 4; ++r) {
        int m = m0 + wr * 64 + i * 16 + lq * 4 + r;
        float v = acc[i][j][r] + bn;
        v = fmaxf(v, 0.0f);                          // relu before residual
        size_t orow = (size_t)m;
        if (OUTPAD || RESIDUAL) {
          int bb = m >> 9, ll = m & 511;
          size_t prow = (size_t)bb * LP_ + ll + 1;
          if (RESIDUAL) v += bf2f(res[prow * D_ + col]);
          if (OUTPAD) orow = prow;
        }
        outb[orow * (size_t)ldo + col] = f2bf(v);
      }
    }
  }
}

// ---------------- span max gather: maxed[p,:] = max(head) + max(tail) -------
// 192 threads x short4: 8 B/lane, 1536 B contiguous per row read.
__global__ void span_kernel(const unsigned short* __restrict__ x2,
                            const int* __restrict__ pb, const int* __restrict__ hi,
                            const int* __restrict__ hs, const int* __restrict__ ti,
                            const int* __restrict__ ts,
                            unsigned short* __restrict__ maxed) {
  const int p = blockIdx.x, t = threadIdx.x;        // 192 threads, 4 cols each
  const int b = pb[p];
  const unsigned short* xb = x2 + (size_t)b * L_ * D_ + t * 4;

  float mh[4], mt[4];
#pragma unroll
  for (int j = 0; j < 4; ++j) { mh[j] = -1e30f; mt[j] = -1e30f; }
  {
    int idx = hi[p], sp = hs[p];
    for (int s = 0; s < sp; ++s) {
      int pos = idx + s; if (pos > L_ - 1) pos = L_ - 1;
      sh4 v = *(const sh4*)(xb + (size_t)pos * D_);
#pragma unroll
      for (int j = 0; j < 4; ++j) mh[j] = fmaxf(mh[j], bf2f((unsigned short)v[j]));
    }
  }
  {
    int idx = ti[p], sp = ts[p];
    for (int s = 0; s < sp; ++s) {
      int pos = idx + s; if (pos > L_ - 1) pos = L_ - 1;
      sh4 v = *(const sh4*)(xb + (size_t)pos * D_);
#pragma unroll
      for (int j = 0; j < 4; ++j) mt[j] = fmaxf(mt[j], bf2f((unsigned short)v[j]));
    }
  }
  sh4 o;
#pragma unroll
  for (int j = 0; j < 4; ++j) o[j] = (short)f2bf(mh[j] + mt[j]);
  *(sh4*)(maxed + (size_t)p * D_ + t * 4) = o;
}

// ---------------- rel head: logits[p,r] = h2[p,:]·rel_w[r,:] + rel_b --------
__global__ void rel_kernel(const unsigned short* __restrict__ h2,
                           const float* __restrict__ rw, const float* __restrict__ rb,
                           const int* __restrict__ labels, float* __restrict__ out) {
  const int wave = threadIdx.x >> 6, lane = threadIdx.x & 63;
  const int p = blockIdx.x * 4 + wave;              // 1 wave per pair
  float a[16];
#pragma unroll
  for (int j = 0; j < 16; ++j) a[j] = bf2f(h2[(size_t)p * H_ + lane + j * 64]);
  for (int r = 0; r < R_; ++r) {
    float s = 0.f;
    const float* wrow = rw + (size_t)r * H_;
#pragma unroll
    for (int j = 0; j < 16; ++j) s += a[j] * wrow[lane + j * 64];
#pragma unroll
    for (int m = 32; m >= 1; m >>= 1) s += __shfl_xor(s, m);
    if (lane == 0) out[(size_t)p * R_ + r] = s + rb[r];
  }
  if (threadIdx.x < 4) {
    int pp = blockIdx.x * 4 + threadIdx.x;
    out[(size_t)P_ * R_ + pp] = (float)labels[pp];
  }
}

extern "C" void kernel_launch(void* const* d_in, const int* in_sizes, int n_in,
                              void* d_out, int out_size, void* d_ws, size_t ws_size,
                              hipStream_t stream) {
  const float* x      = (const float*)d_in[0];
  const int*   pb     = (const int*)d_in[1];
  const int*   hi     = (const int*)d_in[2];
  const int*   hs     = (const int*)d_in[3];
  const int*   ti     = (const int*)d_in[4];
  const int*   ts     = (const int*)d_in[5];
  const int*   labels = (const int*)d_in[6];
  const float* w1     = (const float*)d_in[7];
  const float* b1     = (const float*)d_in[8];
  const float* w2     = (const float*)d_in[9];
  const float* b2     = (const float*)d_in[10];
  const float* l1w    = (const float*)d_in[11];
  const float* l1bias = (const float*)d_in[12];
  const float* l2w    = (const float*)d_in[13];
  const float* l2bias = (const float*)d_in[14];
  const float* rw     = (const float*)d_in[15];
  const float* rbias  = (const float*)d_in[16];
  float* out = (float*)d_out;

  unsigned short* ws    = (unsigned short*)d_ws;
  unsigned short* xpad0 = ws;                                   // B*LP*D
  unsigned short* xpad1 = xpad0 + (size_t)B_ * LP_ * D_;        // B*LP*D
  unsigned short* x2    = xpad1 + (size_t)B_ * LP_ * D_;        // B*L*D
  unsigned short* wt1   = x2    + (size_t)B_ * L_ * D_;         // D*3*D
  unsigned short* wt2   = wt1   + (size_t)D_ * 3 * D_;
  unsigned short* l1b   = wt2   + (size_t)D_ * 3 * D_;          // H*D
  unsigned short* l2b   = l1b   + (size_t)H_ * D_;              // H*H
  // xpad0 is dead after conv GEMM1 -> reuse for maxed/h1/h2 (11.5M <= 12.6M elems)
  unsigned short* maxed = xpad0;                                // P*D
  unsigned short* h1    = xpad0 + (size_t)P_ * D_;              // P*H
  unsigned short* h2    = h1    + (size_t)P_ * H_;              // P*H

  transpose_pad_kernel<<<dim3(L_ / 32, D_ / 32, B_), dim3(32, 8, 1), 0, stream>>>(x, xpad0);
  zero_pad_kernel<<<(B_ * D_) / 256, 256, 0, stream>>>(xpad0, xpad1);
  prep_w_kernel<<<(D_ * D_ * 3) / 256, 256, 0, stream>>>(w1, w2, l1w, l2w, wt1, wt2, l1b, l2b);

  // conv1: relu(conv(x)+b1) + x -> xpad1 (padded bf16)
  gemm_kernel<true, true, true><<<dim3(D_ / 128, (B_ * L_) / 128), 256, 0, stream>>>(
      xpad0, D_, wt1, K1_, b1, xpad0, xpad1, D_);
  // conv2: relu(conv(x1)+b2) + x1 -> x2 (non-padded bf16)
  gemm_kernel<true, true, false><<<dim3(D_ / 128, (B_ * L_) / 128), 256, 0, stream>>>(
      xpad1, D_, wt2, K1_, b2, xpad1, x2, D_);

  span_kernel<<<P_, 192, 0, stream>>>(x2, pb, hi, hs, ti, ts, maxed);

  // lin1: relu(maxed @ l1w^T + b) -> h1
  gemm_kernel<false, false, false><<<dim3(H_ / 128, P_ / 128), 256, 0, stream>>>(
      maxed, D_, l1b, D_, l1bias, nullptr, h1, H_);
  // lin2: relu(h1 @ l2w^T + b) -> h2
  gemm_kernel<false, false, false><<<dim3(H_ / 128, P_ / 128), 256, 0, stream>>>(
      h1, H_, l2b, H_, l2bias, nullptr, h2, H_);

  rel_kernel<<<P_ / 4, 256, 0, stream>>>(h2, rw, rbias, labels, out);
}

// Round 6
// 361.236 us; speedup vs baseline: 1.2889x; 1.0132x over previous
//
#include <hip/hip_runtime.h>

// RelationExtraction forward: 2x conv1d(D=768,W=3)+relu+residual -> span-max
// gather -> 2x linear+relu -> rel logits. GEMMs: bf16 MFMA 16x16x32, fp32
// accum, 128x128 tile, 3-buffer LDS pipeline with counted vmcnt (T3+T4),
// bijective XCD-chunked block swizzle (T1), 4-slot XOR LDS swizzle (T2,
// both-sides: pre-swizzled global source + swizzled ds_read).

#define B_  32
#define D_  768
#define L_  512
#define LP_ 514          // L + 2 zero-pad rows per batch
#define H_  1024
#define R_  20
#define P_  4096
#define K1_ 2304         // 3*D, conv implicit-GEMM K

typedef __attribute__((ext_vector_type(8))) short sh8;
typedef __attribute__((ext_vector_type(4))) short sh4;
typedef __attribute__((ext_vector_type(4))) float f32x4;

__device__ __forceinline__ float bf2f(unsigned short u) {
  union { unsigned u; float f; } c; c.u = ((unsigned)u) << 16; return c.f;
}
__device__ __forceinline__ unsigned short f2bf(float f) {
  union { float f; unsigned u; } c; c.f = f;
  unsigned u = c.u + 0x7fffu + ((c.u >> 16) & 1u);   // RNE
  return (unsigned short)(u >> 16);
}
__device__ __forceinline__ void gld16(const void* g, void* l) {
  __builtin_amdgcn_global_load_lds((const __attribute__((address_space(1))) void*)g,
                                   (__attribute__((address_space(3))) void*)l,
                                   16, 0, 0);
}

// ---------------- transpose (B,D,L) f32 -> xpad (B,LP,D) bf16 interior ------
// Also zeroes the pad rows of both padded buffers (blocks with l0==0).
__global__ void transpose_pad_kernel(const float* __restrict__ x,
                                     unsigned short* __restrict__ xpad,
                                     unsigned short* __restrict__ xpad1) {
  __shared__ float tile[32][33];
  const int b = blockIdx.z;
  const int l0 = blockIdx.x * 32, d0 = blockIdx.y * 32;
  const int tx = threadIdx.x, ty = threadIdx.y;   // 32 x 8
#pragma unroll
  for (int r = 0; r < 4; ++r)
    tile[ty + r * 8][tx] = x[((size_t)b * D_ + d0 + ty + r * 8) * L_ + l0 + tx];
  if (l0 == 0 && ty < 4) {                        // zero pad rows (both bufs)
    size_t row = (ty & 1) ? ((size_t)b * LP_ + LP_ - 1) * D_ : (size_t)b * LP_ * D_;
    unsigned short* dst = (ty < 2) ? xpad : xpad1;
    dst[row + d0 + tx] = 0;
  }
  __syncthreads();
#pragma unroll
  for (int r = 0; r < 4; ++r) {
    int l = l0 + ty + r * 8, d = d0 + tx;
    xpad[((size_t)b * LP_ + 1 + l) * D_ + d] = f2bf(tile[tx][ty + r * 8]);
  }
}

// ---------------- weight prep: conv (O,I,W)->(O,W,I) bf16; linears -> bf16 --
// Coalesced: thread (o,c) reads 3 consecutive floats, writes 3 coalesced
// streams at stride D_.
__global__ void prep_w_kernel(const float* __restrict__ w1, const float* __restrict__ w2,
                              const float* __restrict__ l1, const float* __restrict__ l2,
                              unsigned short* __restrict__ wt1, unsigned short* __restrict__ wt2,
                              unsigned short* __restrict__ l1b, unsigned short* __restrict__ l2b) {
  int i = blockIdx.x * 256 + threadIdx.x;           // grid covers H_*H_
  if (i < D_ * D_) {
    int o = i / D_, c = i % D_;
    const float* s1 = w1 + (size_t)i * 3;
    const float* s2 = w2 + (size_t)i * 3;
    size_t dbase = (size_t)o * 3 * D_ + c;
#pragma unroll
    for (int k = 0; k < 3; ++k) {
      wt1[dbase + (size_t)k * D_] = f2bf(s1[k]);
      wt2[dbase + (size_t)k * D_] = f2bf(s2[k]);
    }
  }
  if (i < H_ * D_) l1b[i] = f2bf(l1[i]);
  if (i < H_ * H_) l2b[i] = f2bf(l2[i]);
}

// ---------------- GEMM: C[m,n] = act(sum_k A[m,k]*Bw[n,k] + bias[n]) (+res) -
// APAD: A rows live in a (B,LP,D) padded buffer (conv implicit GEMM, lda=D_).
// RESIDUAL: add bf16 residual read from padded buffer row (b*LP+l+1).
// OUTPAD: write output to padded buffer row (b*LP+l+1), else row m.
// T1: bijective XCD-chunked swizzle. T3+T4: 3-buffer pipeline, stage 2 ahead,
// counted s_waitcnt vmcnt(4). T2: 4-slot XOR swizzle — LDS row r (64B = 4x16B
// slots) stores global slot (s ^ (r&3)) at slot s. Staging achieves this with
// a per-lane constant source offset (gload_lds global addr is per-lane; LDS
// dest stays wave-linear). Fragment ds_reads apply the same XOR. 8-way -> 4-way
// bank conflict.
template<bool APAD, bool RESIDUAL, bool OUTPAD>
__global__ __launch_bounds__(256)
void gemm_kernel(const unsigned short* __restrict__ A, int lda,
                 const unsigned short* __restrict__ Bw, int K,
                 const float* __restrict__ bias,
                 const unsigned short* __restrict__ res,
                 unsigned short* __restrict__ outb, int ldo) {
  __shared__ unsigned short Atile[3][128 * 32];
  __shared__ unsigned short Btile[3][128 * 32];

  const int tid  = threadIdx.x;
  const int wave = tid >> 6;
  const int lane = tid & 63;
  const int wr = wave >> 1, wc = wave & 1;          // 2x2 waves -> 64x64 each

  // XCD-chunked bijective swizzle (nwg % 8 == 0 for all our grids)
  const int nwg  = gridDim.x * gridDim.y;
  const int orig = blockIdx.y * gridDim.x + blockIdx.x;
  int bswz = orig;
  if ((nwg & 7) == 0) bswz = (orig & 7) * (nwg >> 3) + (orig >> 3);
  const int m0 = (bswz / gridDim.x) * 128;
  const int n0 = (bswz % gridDim.x) * 128;

  int arow0;
  if (APAD) arow0 = (m0 >> 9) * LP_ + (m0 & 511);   // tile fully inside batch
  else      arow0 = m0;

  f32x4 acc[4][4];
#pragma unroll
  for (int i = 0; i < 4; ++i)
#pragma unroll
    for (int j = 0; j < 4; ++j) acc[i][j] = (f32x4)(0.0f);

  const int srow = lane >> 2;                       // 0..15 row within chunk
  // T2 source pre-swizzle: slot' = (lane&3) ^ (row&3); row&3 == (lane>>2)&3
  const int scol = (((lane & 3) ^ ((lane >> 2) & 3)) * 8);
  const int l16 = lane & 15, lq = lane >> 4;
  const int lsw = (lq ^ (l16 & 3)) * 8;             // T2 read-side slot XOR

  const unsigned short* Ab = A + (size_t)arow0 * lda + scol;
  const unsigned short* Bb = Bw + (size_t)n0 * K + scol;
  const int c0 = wave * 2, c1 = wave * 2 + 1;       // this wave's LDS chunks
  const int rowA0 = c0 * 16 + srow, rowA1 = c1 * 16 + srow;

#define STAGE(buf, kk) do {                                          \
    gld16(Ab + (size_t)rowA0 * lda + (kk), &Atile[buf][c0 * 512]);   \
    gld16(Bb + (size_t)rowA0 * K   + (kk), &Btile[buf][c0 * 512]);   \
    gld16(Ab + (size_t)rowA1 * lda + (kk), &Atile[buf][c1 * 512]);   \
    gld16(Bb + (size_t)rowA1 * K   + (kk), &Btile[buf][c1 * 512]);   \
  } while (0)

  const int nIter = K >> 5;                          // K/32, >= 3 for all uses
  STAGE(0, 0);                                       // 4 loads in flight
  STAGE(1, 32);                                      // 8 loads in flight

  int cur = 0;
  for (int t = 0; t < nIter; ++t) {
    // wait for own iter-t loads (4 newer ones may stay in flight), then sync
    if (t + 1 < nIter) asm volatile("s_waitcnt vmcnt(4)" ::: "memory");
    else               asm volatile("s_waitcnt vmcnt(0)" ::: "memory");
    __builtin_amdgcn_s_barrier();

    sh8 af[4], bfr[4];
#pragma unroll
    for (int i = 0; i < 4; ++i)
      af[i] = *(const sh8*)&Atile[cur][(wr * 64 + i * 16 + l16) * 32 + lsw];
#pragma unroll
    for (int j = 0; j < 4; ++j)
      bfr[j] = *(const sh8*)&Btile[cur][(wc * 64 + j * 16 + l16) * 32 + lsw];

    if (t + 2 < nIter) {                             // stage 2 steps ahead
      int sb = cur + 2; if (sb >= 3) sb -= 3;        // (t+2)%3
      STAGE(sb, (t + 2) * 32);
    }

#pragma unroll
    for (int i = 0; i < 4; ++i)
#pragma unroll
      for (int j = 0; j < 4; ++j)
        acc[i][j] = __builtin_amdgcn_mfma_f32_16x16x32_bf16(af[i], bfr[j], acc[i][j], 0, 0, 0);

    cur = (cur == 2) ? 0 : cur + 1;
  }
#undef STAGE

#pragma unroll
  for (int i = 0; i < 4; ++i) {
#pragma unroll
    for (int j = 0; j < 4; ++j) {
      int col = n0 + wc * 64 + j * 16 + l16;
      float bn = bias[col];
#pragma unroll
      for (int r = 0; r < 4; ++r) {
        int m = m0 + wr * 64 + i * 16 + lq * 4 + r;
        float v = acc[i][j][r] + bn;
        v = fmaxf(v, 0.0f);                          // relu before residual
        size_t orow = (size_t)m;
        if (OUTPAD || RESIDUAL) {
          int bb = m >> 9, ll = m & 511;
          size_t prow = (size_t)bb * LP_ + ll + 1;
          if (RESIDUAL) v += bf2f(res[prow * D_ + col]);
          if (OUTPAD) orow = prow;
        }
        outb[orow * (size_t)ldo + col] = f2bf(v);
      }
    }
  }
}

// ---------------- counting-sort pairs by batch (one block, 1024 threads) ----
// perm output order within a batch is nondeterministic (atomics), but span
// output is indexed by the original pair id -> result deterministic.
__global__ void span_sort_kernel(const int* __restrict__ pb, int* __restrict__ perm) {
  __shared__ int cnt[B_], off[B_];
  const int t = threadIdx.x;                        // 1024 threads, 4 pairs each
  if (t < B_) cnt[t] = 0;
  __syncthreads();
  int bv[4];
#pragma unroll
  for (int r = 0; r < 4; ++r) { bv[r] = pb[t * 4 + r]; atomicAdd(&cnt[bv[r]], 1); }
  __syncthreads();
  if (t == 0) { int s = 0; for (int i = 0; i < B_; ++i) { off[i] = s; s += cnt[i]; } }
  __syncthreads();
#pragma unroll
  for (int r = 0; r < 4; ++r) {
    int pos = atomicAdd(&off[bv[r]], 1);
    perm[pos] = t * 4 + r;
  }
}

// ---------------- span max gather: maxed[p,:] = max(head) + max(tail) -------
// Blocks pick batch-sorted pairs via XCD-chunked index -> each XCD works a
// contiguous batch range (~6 MB of x2) that stays L2-resident.
__global__ void span_kernel(const unsigned short* __restrict__ x2,
                            const int* __restrict__ perm,
                            const int* __restrict__ pb, const int* __restrict__ hi,
                            const int* __restrict__ hs, const int* __restrict__ ti,
                            const int* __restrict__ ts,
                            unsigned short* __restrict__ maxed) {
  const int sidx = (blockIdx.x & 7) * (P_ / 8) + (blockIdx.x >> 3);
  const int p = perm[sidx];
  const int t = threadIdx.x;                        // 192 threads, 4 cols each
  const int b = pb[p];
  const unsigned short* xb = x2 + (size_t)b * L_ * D_ + t * 4;

  float mh[4], mt[4];
#pragma unroll
  for (int j = 0; j < 4; ++j) { mh[j] = -1e30f; mt[j] = -1e30f; }
  {
    int idx = hi[p], sp = hs[p];
    for (int s = 0; s < sp; ++s) {
      int pos = idx + s; if (pos > L_ - 1) pos = L_ - 1;
      sh4 v = *(const sh4*)(xb + (size_t)pos * D_);
#pragma unroll
      for (int j = 0; j < 4; ++j) mh[j] = fmaxf(mh[j], bf2f((unsigned short)v[j]));
    }
  }
  {
    int idx = ti[p], sp = ts[p];
    for (int s = 0; s < sp; ++s) {
      int pos = idx + s; if (pos > L_ - 1) pos = L_ - 1;
      sh4 v = *(const sh4*)(xb + (size_t)pos * D_);
#pragma unroll
      for (int j = 0; j < 4; ++j) mt[j] = fmaxf(mt[j], bf2f((unsigned short)v[j]));
    }
  }
  sh4 o;
#pragma unroll
  for (int j = 0; j < 4; ++j) o[j] = (short)f2bf(mh[j] + mt[j]);
  *(sh4*)(maxed + (size_t)p * D_ + t * 4) = o;
}

// ---------------- rel head: logits[p,r] = h2[p,:]·rel_w[r,:] + rel_b --------
__global__ void rel_kernel(const unsigned short* __restrict__ h2,
                           const float* __restrict__ rw, const float* __restrict__ rb,
                           const int* __restrict__ labels, float* __restrict__ out) {
  const int wave = threadIdx.x >> 6, lane = threadIdx.x & 63;
  const int p = blockIdx.x * 4 + wave;              // 1 wave per pair
  float a[16];
#pragma unroll
  for (int j = 0; j < 16; ++j) a[j] = bf2f(h2[(size_t)p * H_ + lane + j * 64]);
  for (int r = 0; r < R_; ++r) {
    float s = 0.f;
    const float* wrow = rw + (size_t)r * H_;
#pragma unroll
    for (int j = 0; j < 16; ++j) s += a[j] * wrow[lane + j * 64];
#pragma unroll
    for (int m = 32; m >= 1; m >>= 1) s += __shfl_xor(s, m);
    if (lane == 0) out[(size_t)p * R_ + r] = s + rb[r];
  }
  if (threadIdx.x < 4) {
    int pp = blockIdx.x * 4 + threadIdx.x;
    out[(size_t)P_ * R_ + pp] = (float)labels[pp];
  }
}

extern "C" void kernel_launch(void* const* d_in, const int* in_sizes, int n_in,
                              void* d_out, int out_size, void* d_ws, size_t ws_size,
                              hipStream_t stream) {
  const float* x      = (const float*)d_in[0];
  const int*   pb     = (const int*)d_in[1];
  const int*   hi     = (const int*)d_in[2];
  const int*   hs     = (const int*)d_in[3];
  const int*   ti     = (const int*)d_in[4];
  const int*   ts     = (const int*)d_in[5];
  const int*   labels = (const int*)d_in[6];
  const float* w1     = (const float*)d_in[7];
  const float* b1     = (const float*)d_in[8];
  const float* w2     = (const float*)d_in[9];
  const float* b2     = (const float*)d_in[10];
  const float* l1w    = (const float*)d_in[11];
  const float* l1bias = (const float*)d_in[12];
  const float* l2w    = (const float*)d_in[13];
  const float* l2bias = (const float*)d_in[14];
  const float* rw     = (const float*)d_in[15];
  const float* rbias  = (const float*)d_in[16];
  float* out = (float*)d_out;

  unsigned short* ws    = (unsigned short*)d_ws;
  unsigned short* xpad0 = ws;                                   // B*LP*D
  unsigned short* xpad1 = xpad0 + (size_t)B_ * LP_ * D_;        // B*LP*D
  unsigned short* x2    = xpad1 + (size_t)B_ * LP_ * D_;        // B*L*D
  unsigned short* wt1   = x2    + (size_t)B_ * L_ * D_;         // D*3*D
  unsigned short* wt2   = wt1   + (size_t)D_ * 3 * D_;
  unsigned short* l1b   = wt2   + (size_t)D_ * 3 * D_;          // H*D
  unsigned short* l2b   = l1b   + (size_t)H_ * D_;              // H*H
  // xpad0 dead after conv GEMM1 -> reuse for maxed/h1/h2
  unsigned short* maxed = xpad0;                                // P*D
  unsigned short* h1    = xpad0 + (size_t)P_ * D_;              // P*H
  unsigned short* h2    = h1    + (size_t)P_ * H_;              // P*H
  // wt1 dead after conv GEMM2 -> reuse for pair permutation (4096 ints)
  int* perm = (int*)wt1;

  transpose_pad_kernel<<<dim3(L_ / 32, D_ / 32, B_), dim3(32, 8, 1), 0, stream>>>(x, xpad0, xpad1);
  prep_w_kernel<<<(H_ * H_) / 256, 256, 0, stream>>>(w1, w2, l1w, l2w, wt1, wt2, l1b, l2b);

  // conv1: relu(conv(x)+b1) + x -> xpad1 (padded bf16)
  gemm_kernel<true, true, true><<<dim3(D_ / 128, (B_ * L_) / 128), 256, 0, stream>>>(
      xpad0, D_, wt1, K1_, b1, xpad0, xpad1, D_);
  // conv2: relu(conv(x1)+b2) + x1 -> x2 (non-padded bf16)
  gemm_kernel<true, true, false><<<dim3(D_ / 128, (B_ * L_) / 128), 256, 0, stream>>>(
      xpad1, D_, wt2, K1_, b2, xpad1, x2, D_);

  span_sort_kernel<<<1, 1024, 0, stream>>>(pb, perm);
  span_kernel<<<P_, 192, 0, stream>>>(x2, perm, pb, hi, hs, ti, ts, maxed);

  // lin1: relu(maxed @ l1w^T + b) -> h1
  gemm_kernel<false, false, false><<<dim3(H_ / 128, P_ / 128), 256, 0, stream>>>(
      maxed, D_, l1b, D_, l1bias, nullptr, h1, H_);
  // lin2: relu(h1 @ l2w^T + b) -> h2
  gemm_kernel<false, false, false><<<dim3(H_ / 128, P_ / 128), 256, 0, stream>>>(
      h1, H_, l2b, H_, l2bias, nullptr, h2, H_);

  rel_kernel<<<P_ / 4, 256, 0, stream>>>(h2, rw, rbias, labels, out);
}

// Round 9
// 338.960 us; speedup vs baseline: 1.3736x; 1.0657x over previous
//
#include <hip/hip_runtime.h>

// RelationExtraction forward: 2x conv1d(D=768,W=3)+relu+residual -> span-max
// gather -> 2x linear+relu -> rel logits. Conv GEMMs: 256x128 tile, wave tile
// 128x64 (halves LDS bytes/FLOP), BK=32, 3-buffer counted-vmcnt pipeline,
// setprio around MFMA. Lin GEMMs: proven 128x128 kernel. T1 XCD swizzle on all.

#define B_  32
#define D_  768
#define L_  512
#define LP_ 514          // L + 2 zero-pad rows per batch
#define H_  1024
#define R_  20
#define P_  4096
#define K1_ 2304         // 3*D, conv implicit-GEMM K

typedef __attribute__((ext_vector_type(8))) short sh8;
typedef __attribute__((ext_vector_type(4))) short sh4;
typedef __attribute__((ext_vector_type(4))) float f32x4;

__device__ __forceinline__ float bf2f(unsigned short u) {
  union { unsigned u; float f; } c; c.u = ((unsigned)u) << 16; return c.f;
}
__device__ __forceinline__ unsigned short f2bf(float f) {
  union { float f; unsigned u; } c; c.f = f;
  unsigned u = c.u + 0x7fffu + ((c.u >> 16) & 1u);   // RNE
  return (unsigned short)(u >> 16);
}
__device__ __forceinline__ void gld16(const void* g, void* l) {
  __builtin_amdgcn_global_load_lds((const __attribute__((address_space(1))) void*)g,
                                   (__attribute__((address_space(3))) void*)l,
                                   16, 0, 0);
}

// ---------------- transpose (B,D,L) f32 -> xpad (B,LP,D) bf16 interior ------
__global__ void transpose_pad_kernel(const float* __restrict__ x,
                                     unsigned short* __restrict__ xpad,
                                     unsigned short* __restrict__ xpad1) {
  __shared__ float tile[32][33];
  const int b = blockIdx.z;
  const int l0 = blockIdx.x * 32, d0 = blockIdx.y * 32;
  const int tx = threadIdx.x, ty = threadIdx.y;   // 32 x 8
#pragma unroll
  for (int r = 0; r < 4; ++r)
    tile[ty + r * 8][tx] = x[((size_t)b * D_ + d0 + ty + r * 8) * L_ + l0 + tx];
  if (l0 == 0 && ty < 4) {                        // zero pad rows (both bufs)
    size_t row = (ty & 1) ? ((size_t)b * LP_ + LP_ - 1) * D_ : (size_t)b * LP_ * D_;
    unsigned short* dst = (ty < 2) ? xpad : xpad1;
    dst[row + d0 + tx] = 0;
  }
  __syncthreads();
#pragma unroll
  for (int r = 0; r < 4; ++r) {
    int l = l0 + ty + r * 8, d = d0 + tx;
    xpad[((size_t)b * LP_ + 1 + l) * D_ + d] = f2bf(tile[tx][ty + r * 8]);
  }
}

// ---------------- weight prep: conv (O,I,W)->(O,W,I) bf16; linears -> bf16 --
__global__ void prep_w_kernel(const float* __restrict__ w1, const float* __restrict__ w2,
                              const float* __restrict__ l1, const float* __restrict__ l2,
                              unsigned short* __restrict__ wt1, unsigned short* __restrict__ wt2,
                              unsigned short* __restrict__ l1b, unsigned short* __restrict__ l2b) {
  int i = blockIdx.x * 256 + threadIdx.x;           // grid covers H_*H_
  if (i < D_ * D_) {
    int o = i / D_, c = i % D_;
    const float* s1 = w1 + (size_t)i * 3;
    const float* s2 = w2 + (size_t)i * 3;
    size_t dbase = (size_t)o * 3 * D_ + c;
#pragma unroll
    for (int k = 0; k < 3; ++k) {
      wt1[dbase + (size_t)k * D_] = f2bf(s1[k]);
      wt2[dbase + (size_t)k * D_] = f2bf(s2[k]);
    }
  }
  if (i < H_ * D_) l1b[i] = f2bf(l1[i]);
  if (i < H_ * H_) l2b[i] = f2bf(l2[i]);
}

// ============ conv GEMM: 256x128 tile, 4 waves, wave tile 128x64 ============
// A rows in (B,LP,D) padded buffer (implicit conv GEMM). Output relu(.+bias)
// + residual; OUTPAD selects padded/non-padded destination.
// 3 buffers, stage full tile t+2 each iter (6 gld16/thread), boundary
// s_waitcnt vmcnt(6): FIFO retires tile-t's batch (issued 2 iters ago) while
// tile-(t+1)'s 6 loads stay in flight across the barrier. Safe by the same
// argument as the 128^2 kernel (all ds_reads consumed before the barrier).
template<bool RESIDUAL, bool OUTPAD>
__global__ __launch_bounds__(256, 2)
void gemm256_kernel(const unsigned short* __restrict__ A, int lda,
                    const unsigned short* __restrict__ Bw, int K,
                    const float* __restrict__ bias,
                    const unsigned short* __restrict__ res,
                    unsigned short* __restrict__ outb, int ldo) {
  __shared__ unsigned short Atile[3][256 * 32];     // 48 KB
  __shared__ unsigned short Btile[3][128 * 32];     // 24 KB
  const int tid  = threadIdx.x;
  const int wave = tid >> 6;
  const int lane = tid & 63;
  const int wr = wave >> 1, wc = wave & 1;          // wave tile 128x64

  const int nwg  = gridDim.x * gridDim.y;           // 384 (%8==0)
  const int orig = blockIdx.y * gridDim.x + blockIdx.x;
  const int bswz = (orig & 7) * (nwg >> 3) + (orig >> 3);
  const int m0 = (bswz / gridDim.x) * 256;
  const int n0 = (bswz % gridDim.x) * 128;
  const int arow0 = (m0 >> 9) * LP_ + (m0 & 511);   // 256-row tile inside batch

  f32x4 acc[8][4];
#pragma unroll
  for (int i = 0; i < 8; ++i)
#pragma unroll
    for (int j = 0; j < 4; ++j) acc[i][j] = (f32x4)(0.0f);

  const int srow = lane >> 2, scol = (lane & 3) * 8;
  const int l16 = lane & 15, lq = lane >> 4;

  // staging bases: wave w covers rows {s*64 + w*16 + srow}, s = sweep
  const unsigned short* Ab = A + (size_t)(arow0 + wave * 16 + srow) * lda + scol;
  const unsigned short* Bb = Bw + (size_t)(n0 + wave * 16 + srow) * K + scol;

#define STG256(buf, kk) do {                                              \
    gld16(Ab + (size_t)(0 * 64) * lda + (kk), &Atile[buf][0 * 2048 + wave * 512]); \
    gld16(Ab + (size_t)(1 * 64) * lda + (kk), &Atile[buf][1 * 2048 + wave * 512]); \
    gld16(Ab + (size_t)(2 * 64) * lda + (kk), &Atile[buf][2 * 2048 + wave * 512]); \
    gld16(Ab + (size_t)(3 * 64) * lda + (kk), &Atile[buf][3 * 2048 + wave * 512]); \
    gld16(Bb + (size_t)(0 * 64) * K   + (kk), &Btile[buf][0 * 2048 + wave * 512]); \
    gld16(Bb + (size_t)(1 * 64) * K   + (kk), &Btile[buf][1 * 2048 + wave * 512]); \
  } while (0)

  const int nIter = K >> 5;                          // 72 for conv
  STG256(0, 0);
  STG256(1, 32);

  int cur = 0;
  for (int t = 0; t < nIter; ++t) {
    if (t + 1 < nIter) asm volatile("s_waitcnt vmcnt(6)" ::: "memory");
    else               asm volatile("s_waitcnt vmcnt(0)" ::: "memory");
    __builtin_amdgcn_s_barrier();

    sh8 bfrag[4], afrag[8];
#pragma unroll
    for (int j = 0; j < 4; ++j)
      bfrag[j] = *(const sh8*)&Btile[cur][(wc * 64 + j * 16 + l16) * 32 + lq * 8];
#pragma unroll
    for (int i = 0; i < 8; ++i)
      afrag[i] = *(const sh8*)&Atile[cur][(wr * 128 + i * 16 + l16) * 32 + lq * 8];

    if (t + 2 < nIter) {                             // stage 2 tiles ahead
      int sb = cur + 2; if (sb >= 3) sb -= 3;
      STG256(sb, (t + 2) * 32);
    }

    __builtin_amdgcn_s_setprio(1);
#pragma unroll
    for (int i = 0; i < 8; ++i)
#pragma unroll
      for (int j = 0; j < 4; ++j)
        acc[i][j] = __builtin_amdgcn_mfma_f32_16x16x32_bf16(afrag[i], bfrag[j], acc[i][j], 0, 0, 0);
    __builtin_amdgcn_s_setprio(0);

    cur = (cur == 2) ? 0 : cur + 1;
  }
#undef STG256

#pragma unroll
  for (int i = 0; i < 8; ++i) {
#pragma unroll
    for (int j = 0; j < 4; ++j) {
      int col = n0 + wc * 64 + j * 16 + l16;
      float bn = bias[col];
#pragma unroll
      for (int r = 0; r < 4; ++r) {
        int m = m0 + wr * 128 + i * 16 + lq * 4 + r;
        float v = acc[i][j][r] + bn;
        v = fmaxf(v, 0.0f);                          // relu before residual
        int bb = m >> 9, ll = m & 511;
        size_t prow = (size_t)bb * LP_ + ll + 1;
        if (RESIDUAL) v += bf2f(res[prow * D_ + col]);
        size_t orow = OUTPAD ? prow : (size_t)m;
        outb[orow * (size_t)ldo + col] = f2bf(v);
      }
    }
  }
}

// ============ lin GEMM: proven 128x128, 4 waves, 3-buf counted vmcnt ========
template<bool APAD, bool RESIDUAL, bool OUTPAD>
__global__ __launch_bounds__(256)
void gemm_kernel(const unsigned short* __restrict__ A, int lda,
                 const unsigned short* __restrict__ Bw, int K,
                 const float* __restrict__ bias,
                 const unsigned short* __restrict__ res,
                 unsigned short* __restrict__ outb, int ldo) {
  __shared__ unsigned short Atile[3][128 * 32];
  __shared__ unsigned short Btile[3][128 * 32];

  const int tid  = threadIdx.x;
  const int wave = tid >> 6;
  const int lane = tid & 63;
  const int wr = wave >> 1, wc = wave & 1;          // 2x2 waves -> 64x64 each

  const int nwg  = gridDim.x * gridDim.y;
  const int orig = blockIdx.y * gridDim.x + blockIdx.x;
  int bswz = orig;
  if ((nwg & 7) == 0) bswz = (orig & 7) * (nwg >> 3) + (orig >> 3);
  const int m0 = (bswz / gridDim.x) * 128;
  const int n0 = (bswz % gridDim.x) * 128;

  int arow0;
  if (APAD) arow0 = (m0 >> 9) * LP_ + (m0 & 511);
  else      arow0 = m0;

  f32x4 acc[4][4];
#pragma unroll
  for (int i = 0; i < 4; ++i)
#pragma unroll
    for (int j = 0; j < 4; ++j) acc[i][j] = (f32x4)(0.0f);

  const int srow = lane >> 2;
  const int scol = (((lane & 3) ^ ((lane >> 2) & 3)) * 8);
  const int l16 = lane & 15, lq = lane >> 4;
  const int lsw = (lq ^ (l16 & 3)) * 8;

  const unsigned short* Ab = A + (size_t)arow0 * lda + scol;
  const unsigned short* Bb = Bw + (size_t)n0 * K + scol;
  const int c0 = wave * 2, c1 = wave * 2 + 1;
  const int rowA0 = c0 * 16 + srow, rowA1 = c1 * 16 + srow;

#define STAGE(buf, kk) do {                                          \
    gld16(Ab + (size_t)rowA0 * lda + (kk), &Atile[buf][c0 * 512]);   \
    gld16(Bb + (size_t)rowA0 * K   + (kk), &Btile[buf][c0 * 512]);   \
    gld16(Ab + (size_t)rowA1 * lda + (kk), &Atile[buf][c1 * 512]);   \
    gld16(Bb + (size_t)rowA1 * K   + (kk), &Btile[buf][c1 * 512]);   \
  } while (0)

  const int nIter = K >> 5;
  STAGE(0, 0);
  STAGE(1, 32);

  int cur = 0;
  for (int t = 0; t < nIter; ++t) {
    if (t + 1 < nIter) asm volatile("s_waitcnt vmcnt(4)" ::: "memory");
    else               asm volatile("s_waitcnt vmcnt(0)" ::: "memory");
    __builtin_amdgcn_s_barrier();

    sh8 af[4], bfr[4];
#pragma unroll
    for (int i = 0; i < 4; ++i)
      af[i] = *(const sh8*)&Atile[cur][(wr * 64 + i * 16 + l16) * 32 + lsw];
#pragma unroll
    for (int j = 0; j < 4; ++j)
      bfr[j] = *(const sh8*)&Btile[cur][(wc * 64 + j * 16 + l16) * 32 + lsw];

    if (t + 2 < nIter) {
      int sb = cur + 2; if (sb >= 3) sb -= 3;
      STAGE(sb, (t + 2) * 32);
    }

#pragma unroll
    for (int i = 0; i < 4; ++i)
#pragma unroll
      for (int j = 0; j < 4; ++j)
        acc[i][j] = __builtin_amdgcn_mfma_f32_16x16x32_bf16(af[i], bfr[j], acc[i][j], 0, 0, 0);

    cur = (cur == 2) ? 0 : cur + 1;
  }
#undef STAGE

#pragma unroll
  for (int i = 0; i < 4; ++i) {
#pragma unroll
    for (int j = 0; j < 4; ++j) {
      int col = n0 + wc * 64 + j * 16 + l16;
      float bn = bias[col];
#pragma unroll
      for (int r = 0; r < 4; ++r) {
        int m = m0 + wr * 64 + i * 16 + lq * 4 + r;
        float v = acc[i][j][r] + bn;
        v = fmaxf(v, 0.0f);
        size_t orow = (size_t)m;
        if (OUTPAD || RESIDUAL) {
          int bb = m >> 9, ll = m & 511;
          size_t prow = (size_t)bb * LP_ + ll + 1;
          if (RESIDUAL) v += bf2f(res[prow * D_ + col]);
          if (OUTPAD) orow = prow;
        }
        outb[orow * (size_t)ldo + col] = f2bf(v);
      }
    }
  }
}

// ---------------- counting-sort pairs by batch (one block, 1024 threads) ----
__global__ void span_sort_kernel(const int* __restrict__ pb, int* __restrict__ perm) {
  __shared__ int cnt[B_], off[B_];
  const int t = threadIdx.x;
  if (t < B_) cnt[t] = 0;
  __syncthreads();
  int bv[4];
#pragma unroll
  for (int r = 0; r < 4; ++r) { bv[r] = pb[t * 4 + r]; atomicAdd(&cnt[bv[r]], 1); }
  __syncthreads();
  if (t == 0) { int s = 0; for (int i = 0; i < B_; ++i) { off[i] = s; s += cnt[i]; } }
  __syncthreads();
#pragma unroll
  for (int r = 0; r < 4; ++r) {
    int pos = atomicAdd(&off[bv[r]], 1);
    perm[pos] = t * 4 + r;
  }
}

// ---------------- span max gather: maxed[p,:] = max(head) + max(tail) -------
__global__ void span_kernel(const unsigned short* __restrict__ x2,
                            const int* __restrict__ perm,
                            const int* __restrict__ pb, const int* __restrict__ hi,
                            const int* __restrict__ hs, const int* __restrict__ ti,
                            const int* __restrict__ ts,
                            unsigned short* __restrict__ maxed) {
  const int sidx = (blockIdx.x & 7) * (P_ / 8) + (blockIdx.x >> 3);
  const int p = perm[sidx];
  const int t = threadIdx.x;                        // 192 threads, 4 cols each
  const int b = pb[p];
  const unsigned short* xb = x2 + (size_t)b * L_ * D_ + t * 4;

  float mh[4], mt[4];
#pragma unroll
  for (int j = 0; j < 4; ++j) { mh[j] = -1e30f; mt[j] = -1e30f; }
  {
    int idx = hi[p], sp = hs[p];
    for (int s = 0; s < sp; ++s) {
      int pos = idx + s; if (pos > L_ - 1) pos = L_ - 1;
      sh4 v = *(const sh4*)(xb + (size_t)pos * D_);
#pragma unroll
      for (int j = 0; j < 4; ++j) mh[j] = fmaxf(mh[j], bf2f((unsigned short)v[j]));
    }
  }
  {
    int idx = ti[p], sp = ts[p];
    for (int s = 0; s < sp; ++s) {
      int pos = idx + s; if (pos > L_ - 1) pos = L_ - 1;
      sh4 v = *(const sh4*)(xb + (size_t)pos * D_);
#pragma unroll
      for (int j = 0; j < 4; ++j) mt[j] = fmaxf(mt[j], bf2f((unsigned short)v[j]));
    }
  }
  sh4 o;
#pragma unroll
  for (int j = 0; j < 4; ++j) o[j] = (short)f2bf(mh[j] + mt[j]);
  *(sh4*)(maxed + (size_t)p * D_ + t * 4) = o;
}

// ---------------- rel head: logits[p,r] = h2[p,:]·rel_w[r,:] + rel_b --------
__global__ void rel_kernel(const unsigned short* __restrict__ h2,
                           const float* __restrict__ rw, const float* __restrict__ rb,
                           const int* __restrict__ labels, float* __restrict__ out) {
  const int wave = threadIdx.x >> 6, lane = threadIdx.x & 63;
  const int p = blockIdx.x * 4 + wave;
  float a[16];
#pragma unroll
  for (int j = 0; j < 16; ++j) a[j] = bf2f(h2[(size_t)p * H_ + lane + j * 64]);
  for (int r = 0; r < R_; ++r) {
    float s = 0.f;
    const float* wrow = rw + (size_t)r * H_;
#pragma unroll
    for (int j = 0; j < 16; ++j) s += a[j] * wrow[lane + j * 64];
#pragma unroll
    for (int m = 32; m >= 1; m >>= 1) s += __shfl_xor(s, m);
    if (lane == 0) out[(size_t)p * R_ + r] = s + rb[r];
  }
  if (threadIdx.x < 4) {
    int pp = blockIdx.x * 4 + threadIdx.x;
    out[(size_t)P_ * R_ + pp] = (float)labels[pp];
  }
}

extern "C" void kernel_launch(void* const* d_in, const int* in_sizes, int n_in,
                              void* d_out, int out_size, void* d_ws, size_t ws_size,
                              hipStream_t stream) {
  const float* x      = (const float*)d_in[0];
  const int*   pb     = (const int*)d_in[1];
  const int*   hi     = (const int*)d_in[2];
  const int*   hs     = (const int*)d_in[3];
  const int*   ti     = (const int*)d_in[4];
  const int*   ts     = (const int*)d_in[5];
  const int*   labels = (const int*)d_in[6];
  const float* w1     = (const float*)d_in[7];
  const float* b1     = (const float*)d_in[8];
  const float* w2     = (const float*)d_in[9];
  const float* b2     = (const float*)d_in[10];
  const float* l1w    = (const float*)d_in[11];
  const float* l1bias = (const float*)d_in[12];
  const float* l2w    = (const float*)d_in[13];
  const float* l2bias = (const float*)d_in[14];
  const float* rw     = (const float*)d_in[15];
  const float* rbias  = (const float*)d_in[16];
  float* out = (float*)d_out;

  unsigned short* ws    = (unsigned short*)d_ws;
  unsigned short* xpad0 = ws;                                   // B*LP*D
  unsigned short* xpad1 = xpad0 + (size_t)B_ * LP_ * D_;        // B*LP*D
  unsigned short* x2    = xpad1 + (size_t)B_ * LP_ * D_;        // B*L*D
  unsigned short* wt1   = x2    + (size_t)B_ * L_ * D_;         // D*3*D
  unsigned short* wt2   = wt1   + (size_t)D_ * 3 * D_;
  unsigned short* l1b   = wt2   + (size_t)D_ * 3 * D_;          // H*D
  unsigned short* l2b   = l1b   + (size_t)H_ * D_;              // H*H
  unsigned short* maxed = xpad0;                                // P*D
  unsigned short* h1    = xpad0 + (size_t)P_ * D_;              // P*H
  unsigned short* h2    = h1    + (size_t)P_ * H_;              // P*H
  int* perm = (int*)wt1;                                        // after conv2

  transpose_pad_kernel<<<dim3(L_ / 32, D_ / 32, B_), dim3(32, 8, 1), 0, stream>>>(x, xpad0, xpad1);
  prep_w_kernel<<<(H_ * H_) / 256, 256, 0, stream>>>(w1, w2, l1w, l2w, wt1, wt2, l1b, l2b);

  // conv1: relu(conv(x)+b1) + x -> xpad1 (padded bf16)
  gemm256_kernel<true, true><<<dim3(D_ / 128, (B_ * L_) / 256), 256, 0, stream>>>(
      xpad0, D_, wt1, K1_, b1, xpad0, xpad1, D_);
  // conv2: relu(conv(x1)+b2) + x1 -> x2 (non-padded bf16)
  gemm256_kernel<true, false><<<dim3(D_ / 128, (B_ * L_) / 256), 256, 0, stream>>>(
      xpad1, D_, wt2, K1_, b2, xpad1, x2, D_);

  span_sort_kernel<<<1, 1024, 0, stream>>>(pb, perm);
  span_kernel<<<P_, 192, 0, stream>>>(x2, perm, pb, hi, hs, ti, ts, maxed);

  // lin1: relu(maxed @ l1w^T + b) -> h1
  gemm_kernel<false, false, false><<<dim3(H_ / 128, P_ / 128), 256, 0, stream>>>(
      maxed, D_, l1b, D_, l1bias, nullptr, h1, H_);
  // lin2: relu(h1 @ l2w^T + b) -> h2
  gemm_kernel<false, false, false><<<dim3(H_ / 128, P_ / 128), 256, 0, stream>>>(
      h1, H_, l2b, H_, l2bias, nullptr, h2, H_);

  rel_kernel<<<P_ / 4, 256, 0, stream>>>(h2, rw, rbias, labels, out);
}

// Round 10
// 334.512 us; speedup vs baseline: 1.3919x; 1.0133x over previous
//
#include <hip/hip_runtime.h>

// RelationExtraction forward: 2x conv1d(D=768,W=3)+relu+residual -> span-max
// gather -> 2x linear+relu -> rel logits.
// conv: 256x128 tile, wave tile 128x64, 3-buf counted-vmcnt (proven 78.5us).
// lin:  64x128 tile, 512 blocks = exactly 2/CU (balance + overlap).
// pre:  transpose+pad fused with weight prep (one launch).

#define B_  32
#define D_  768
#define L_  512
#define LP_ 514          // L + 2 zero-pad rows per batch
#define H_  1024
#define R_  20
#define P_  4096
#define K1_ 2304         // 3*D, conv implicit-GEMM K

typedef __attribute__((ext_vector_type(8))) short sh8;
typedef __attribute__((ext_vector_type(4))) short sh4;
typedef __attribute__((ext_vector_type(4))) float f32x4;

__device__ __forceinline__ float bf2f(unsigned short u) {
  union { unsigned u; float f; } c; c.u = ((unsigned)u) << 16; return c.f;
}
__device__ __forceinline__ unsigned short f2bf(float f) {
  union { float f; unsigned u; } c; c.f = f;
  unsigned u = c.u + 0x7fffu + ((c.u >> 16) & 1u);   // RNE
  return (unsigned short)(u >> 16);
}
__device__ __forceinline__ void gld16(const void* g, void* l) {
  __builtin_amdgcn_global_load_lds((const __attribute__((address_space(1))) void*)g,
                                   (__attribute__((address_space(3))) void*)l,
                                   16, 0, 0);
}

// ---- fused pre-pass: blocks [0,12288) transpose (B,D,L)f32 -> (B,LP,D)bf16
//      (+ zero pad rows); blocks [12288,16384) convert/transpose weights. ----
#define TBLK 12288       // 16 * 24 * 32
__global__ void pre_kernel(const float* __restrict__ x,
                           const float* __restrict__ w1, const float* __restrict__ w2,
                           const float* __restrict__ l1, const float* __restrict__ l2,
                           unsigned short* __restrict__ xpad,
                           unsigned short* __restrict__ xpad1,
                           unsigned short* __restrict__ wt1, unsigned short* __restrict__ wt2,
                           unsigned short* __restrict__ l1b, unsigned short* __restrict__ l2b) {
  __shared__ float tile[32][33];
  const int blk = blockIdx.x;
  if (blk < TBLK) {
    const int bx = blk & 15, by = (blk >> 4) % 24, bz = blk / (16 * 24);
    const int l0 = bx * 32, d0 = by * 32, b = bz;
    const int t = threadIdx.x, tx = t & 31, ty = t >> 5;   // 32 x 8
#pragma unroll
    for (int r = 0; r < 4; ++r)
      tile[ty + r * 8][tx] = x[((size_t)b * D_ + d0 + ty + r * 8) * L_ + l0 + tx];
    if (l0 == 0 && ty < 4) {                      // zero pad rows (both bufs)
      size_t row = (ty & 1) ? ((size_t)b * LP_ + LP_ - 1) * D_ : (size_t)b * LP_ * D_;
      unsigned short* dst = (ty < 2) ? xpad : xpad1;
      dst[row + d0 + tx] = 0;
    }
    __syncthreads();
#pragma unroll
    for (int r = 0; r < 4; ++r) {
      int l = l0 + ty + r * 8, d = d0 + tx;
      xpad[((size_t)b * LP_ + 1 + l) * D_ + d] = f2bf(tile[tx][ty + r * 8]);
    }
  } else {
    int i = (blk - TBLK) * 256 + threadIdx.x;     // covers H_*H_
    if (i < D_ * D_) {
      int o = i / D_, c = i % D_;
      const float* s1 = w1 + (size_t)i * 3;
      const float* s2 = w2 + (size_t)i * 3;
      size_t dbase = (size_t)o * 3 * D_ + c;
#pragma unroll
      for (int k = 0; k < 3; ++k) {
        wt1[dbase + (size_t)k * D_] = f2bf(s1[k]);
        wt2[dbase + (size_t)k * D_] = f2bf(s2[k]);
      }
    }
    if (i < H_ * D_) l1b[i] = f2bf(l1[i]);
    if (i < H_ * H_) l2b[i] = f2bf(l2[i]);
  }
}

// ============ conv GEMM: 256x128 tile, 4 waves, wave tile 128x64 ============
// (unchanged from round 9: 78.5us/dispatch, MfmaUtil 31%)
template<bool RESIDUAL, bool OUTPAD>
__global__ __launch_bounds__(256, 2)
void gemm256_kernel(const unsigned short* __restrict__ A, int lda,
                    const unsigned short* __restrict__ Bw, int K,
                    const float* __restrict__ bias,
                    const unsigned short* __restrict__ res,
                    unsigned short* __restrict__ outb, int ldo) {
  __shared__ unsigned short Atile[3][256 * 32];     // 48 KB
  __shared__ unsigned short Btile[3][128 * 32];     // 24 KB
  const int tid  = threadIdx.x;
  const int wave = tid >> 6;
  const int lane = tid & 63;
  const int wr = wave >> 1, wc = wave & 1;          // wave tile 128x64

  const int nwg  = gridDim.x * gridDim.y;           // 384 (%8==0)
  const int orig = blockIdx.y * gridDim.x + blockIdx.x;
  const int bswz = (orig & 7) * (nwg >> 3) + (orig >> 3);
  const int m0 = (bswz / gridDim.x) * 256;
  const int n0 = (bswz % gridDim.x) * 128;
  const int arow0 = (m0 >> 9) * LP_ + (m0 & 511);   // 256-row tile inside batch

  f32x4 acc[8][4];
#pragma unroll
  for (int i = 0; i < 8; ++i)
#pragma unroll
    for (int j = 0; j < 4; ++j) acc[i][j] = (f32x4)(0.0f);

  const int srow = lane >> 2, scol = (lane & 3) * 8;
  const int l16 = lane & 15, lq = lane >> 4;

  const unsigned short* Ab = A + (size_t)(arow0 + wave * 16 + srow) * lda + scol;
  const unsigned short* Bb = Bw + (size_t)(n0 + wave * 16 + srow) * K + scol;

#define STG256(buf, kk) do {                                              \
    gld16(Ab + (size_t)(0 * 64) * lda + (kk), &Atile[buf][0 * 2048 + wave * 512]); \
    gld16(Ab + (size_t)(1 * 64) * lda + (kk), &Atile[buf][1 * 2048 + wave * 512]); \
    gld16(Ab + (size_t)(2 * 64) * lda + (kk), &Atile[buf][2 * 2048 + wave * 512]); \
    gld16(Ab + (size_t)(3 * 64) * lda + (kk), &Atile[buf][3 * 2048 + wave * 512]); \
    gld16(Bb + (size_t)(0 * 64) * K   + (kk), &Btile[buf][0 * 2048 + wave * 512]); \
    gld16(Bb + (size_t)(1 * 64) * K   + (kk), &Btile[buf][1 * 2048 + wave * 512]); \
  } while (0)

  const int nIter = K >> 5;                          // 72 for conv
  STG256(0, 0);
  STG256(1, 32);

  int cur = 0;
  for (int t = 0; t < nIter; ++t) {
    if (t + 1 < nIter) asm volatile("s_waitcnt vmcnt(6)" ::: "memory");
    else               asm volatile("s_waitcnt vmcnt(0)" ::: "memory");
    __builtin_amdgcn_s_barrier();

    sh8 bfrag[4], afrag[8];
#pragma unroll
    for (int j = 0; j < 4; ++j)
      bfrag[j] = *(const sh8*)&Btile[cur][(wc * 64 + j * 16 + l16) * 32 + lq * 8];
#pragma unroll
    for (int i = 0; i < 8; ++i)
      afrag[i] = *(const sh8*)&Atile[cur][(wr * 128 + i * 16 + l16) * 32 + lq * 8];

    if (t + 2 < nIter) {                             // stage 2 tiles ahead
      int sb = cur + 2; if (sb >= 3) sb -= 3;
      STG256(sb, (t + 2) * 32);
    }

    __builtin_amdgcn_s_setprio(1);
#pragma unroll
    for (int i = 0; i < 8; ++i)
#pragma unroll
      for (int j = 0; j < 4; ++j)
        acc[i][j] = __builtin_amdgcn_mfma_f32_16x16x32_bf16(afrag[i], bfrag[j], acc[i][j], 0, 0, 0);
    __builtin_amdgcn_s_setprio(0);

    cur = (cur == 2) ? 0 : cur + 1;
  }
#undef STG256

#pragma unroll
  for (int i = 0; i < 8; ++i) {
#pragma unroll
    for (int j = 0; j < 4; ++j) {
      int col = n0 + wc * 64 + j * 16 + l16;
      float bn = bias[col];
#pragma unroll
      for (int r = 0; r < 4; ++r) {
        int m = m0 + wr * 128 + i * 16 + lq * 4 + r;
        float v = acc[i][j][r] + bn;
        v = fmaxf(v, 0.0f);                          // relu before residual
        int bb = m >> 9, ll = m & 511;
        size_t prow = (size_t)bb * LP_ + ll + 1;
        if (RESIDUAL) v += bf2f(res[prow * D_ + col]);
        size_t orow = OUTPAD ? prow : (size_t)m;
        outb[orow * (size_t)ldo + col] = f2bf(v);
      }
    }
  }
}

// ============ lin GEMM: 64x128 tile, 4 waves (wave tile 32x64) ==============
// 512 blocks = exactly 2/CU: perfect balance + cross-block barrier-slip
// overlap (the 128^2 version ran 256 blocks = 1/CU, fully latency-exposed).
// Same 3-buffer / stage-2-ahead / counted vmcnt(3) discipline (3 loads/iter).
__global__ __launch_bounds__(256, 2)
void gemm64_kernel(const unsigned short* __restrict__ A, int lda,
                   const unsigned short* __restrict__ Bw, int K,
                   const float* __restrict__ bias,
                   unsigned short* __restrict__ outb, int ldo) {
  __shared__ unsigned short Atile[3][64 * 32];      // 12 KB
  __shared__ unsigned short Btile[3][128 * 32];     // 24 KB
  const int tid  = threadIdx.x;
  const int wave = tid >> 6;
  const int lane = tid & 63;
  const int wr = wave >> 1, wc = wave & 1;          // wave tile 32x64

  const int nwg  = gridDim.x * gridDim.y;           // 512 (%8==0)
  const int orig = blockIdx.y * gridDim.x + blockIdx.x;
  const int bswz = (orig & 7) * (nwg >> 3) + (orig >> 3);
  const int m0 = (bswz / gridDim.x) * 64;
  const int n0 = (bswz % gridDim.x) * 128;

  f32x4 acc[2][4];
#pragma unroll
  for (int i = 0; i < 2; ++i)
#pragma unroll
    for (int j = 0; j < 4; ++j) acc[i][j] = (f32x4)(0.0f);

  const int srow = lane >> 2, scol = (lane & 3) * 8;
  const int l16 = lane & 15, lq = lane >> 4;

  const unsigned short* Ab = A + (size_t)(m0 + wave * 16 + srow) * lda + scol;
  const unsigned short* Bb = Bw + (size_t)(n0 + wave * 16 + srow) * K + scol;

#define STG64(buf, kk) do {                                               \
    gld16(Ab + (kk),                        &Atile[buf][wave * 512]);     \
    gld16(Bb + (size_t)(0 * 64) * K + (kk), &Btile[buf][0 * 2048 + wave * 512]); \
    gld16(Bb + (size_t)(1 * 64) * K + (kk), &Btile[buf][1 * 2048 + wave * 512]); \
  } while (0)

  const int nIter = K >> 5;                          // 24 or 32
  STG64(0, 0);
  STG64(1, 32);

  int cur = 0;
  for (int t = 0; t < nIter; ++t) {
    if (t + 1 < nIter) asm volatile("s_waitcnt vmcnt(3)" ::: "memory");
    else               asm volatile("s_waitcnt vmcnt(0)" ::: "memory");
    __builtin_amdgcn_s_barrier();

    sh8 af[2], bfr[4];
#pragma unroll
    for (int i = 0; i < 2; ++i)
      af[i] = *(const sh8*)&Atile[cur][(wr * 32 + i * 16 + l16) * 32 + lq * 8];
#pragma unroll
    for (int j = 0; j < 4; ++j)
      bfr[j] = *(const sh8*)&Btile[cur][(wc * 64 + j * 16 + l16) * 32 + lq * 8];

    if (t + 2 < nIter) {
      int sb = cur + 2; if (sb >= 3) sb -= 3;
      STG64(sb, (t + 2) * 32);
    }

#pragma unroll
    for (int i = 0; i < 2; ++i)
#pragma unroll
      for (int j = 0; j < 4; ++j)
        acc[i][j] = __builtin_amdgcn_mfma_f32_16x16x32_bf16(af[i], bfr[j], acc[i][j], 0, 0, 0);

    cur = (cur == 2) ? 0 : cur + 1;
  }
#undef STG64

#pragma unroll
  for (int i = 0; i < 2; ++i) {
#pragma unroll
    for (int j = 0; j < 4; ++j) {
      int col = n0 + wc * 64 + j * 16 + l16;
      float bn = bias[col];
#pragma unroll
      for (int r = 0; r < 4; ++r) {
        int m = m0 + wr * 32 + i * 16 + lq * 4 + r;
        float v = fmaxf(acc[i][j][r] + bn, 0.0f);
        outb[(size_t)m * ldo + col] = f2bf(v);
      }
    }
  }
}

// ---------------- counting-sort pairs by batch (one block, 1024 threads) ----
__global__ void span_sort_kernel(const int* __restrict__ pb, int* __restrict__ perm) {
  __shared__ int cnt[B_], off[B_];
  const int t = threadIdx.x;
  if (t < B_) cnt[t] = 0;
  __syncthreads();
  int bv[4];
#pragma unroll
  for (int r = 0; r < 4; ++r) { bv[r] = pb[t * 4 + r]; atomicAdd(&cnt[bv[r]], 1); }
  __syncthreads();
  if (t == 0) { int s = 0; for (int i = 0; i < B_; ++i) { off[i] = s; s += cnt[i]; } }
  __syncthreads();
#pragma unroll
  for (int r = 0; r < 4; ++r) {
    int pos = atomicAdd(&off[bv[r]], 1);
    perm[pos] = t * 4 + r;
  }
}

// ---------------- span max gather: maxed[p,:] = max(head) + max(tail) -------
__global__ void span_kernel(const unsigned short* __restrict__ x2,
                            const int* __restrict__ perm,
                            const int* __restrict__ pb, const int* __restrict__ hi,
                            const int* __restrict__ hs, const int* __restrict__ ti,
                            const int* __restrict__ ts,
                            unsigned short* __restrict__ maxed) {
  const int sidx = (blockIdx.x & 7) * (P_ / 8) + (blockIdx.x >> 3);
  const int p = perm[sidx];
  const int t = threadIdx.x;                        // 192 threads, 4 cols each
  const int b = pb[p];
  const unsigned short* xb = x2 + (size_t)b * L_ * D_ + t * 4;

  float mh[4], mt[4];
#pragma unroll
  for (int j = 0; j < 4; ++j) { mh[j] = -1e30f; mt[j] = -1e30f; }
  {
    int idx = hi[p], sp = hs[p];
    for (int s = 0; s < sp; ++s) {
      int pos = idx + s; if (pos > L_ - 1) pos = L_ - 1;
      sh4 v = *(const sh4*)(xb + (size_t)pos * D_);
#pragma unroll
      for (int j = 0; j < 4; ++j) mh[j] = fmaxf(mh[j], bf2f((unsigned short)v[j]));
    }
  }
  {
    int idx = ti[p], sp = ts[p];
    for (int s = 0; s < sp; ++s) {
      int pos = idx + s; if (pos > L_ - 1) pos = L_ - 1;
      sh4 v = *(const sh4*)(xb + (size_t)pos * D_);
#pragma unroll
      for (int j = 0; j < 4; ++j) mt[j] = fmaxf(mt[j], bf2f((unsigned short)v[j]));
    }
  }
  sh4 o;
#pragma unroll
  for (int j = 0; j < 4; ++j) o[j] = (short)f2bf(mh[j] + mt[j]);
  *(sh4*)(maxed + (size_t)p * D_ + t * 4) = o;
}

// ---------------- rel head: logits[p,r] = h2[p,:]·rel_w[r,:] + rel_b --------
__global__ void rel_kernel(const unsigned short* __restrict__ h2,
                           const float* __restrict__ rw, const float* __restrict__ rb,
                           const int* __restrict__ labels, float* __restrict__ out) {
  const int wave = threadIdx.x >> 6, lane = threadIdx.x & 63;
  const int p = blockIdx.x * 4 + wave;
  float a[16];
#pragma unroll
  for (int j = 0; j < 16; ++j) a[j] = bf2f(h2[(size_t)p * H_ + lane + j * 64]);
  for (int r = 0; r < R_; ++r) {
    float s = 0.f;
    const float* wrow = rw + (size_t)r * H_;
#pragma unroll
    for (int j = 0; j < 16; ++j) s += a[j] * wrow[lane + j * 64];
#pragma unroll
    for (int m = 32; m >= 1; m >>= 1) s += __shfl_xor(s, m);
    if (lane == 0) out[(size_t)p * R_ + r] = s + rb[r];
  }
  if (threadIdx.x < 4) {
    int pp = blockIdx.x * 4 + threadIdx.x;
    out[(size_t)P_ * R_ + pp] = (float)labels[pp];
  }
}

extern "C" void kernel_launch(void* const* d_in, const int* in_sizes, int n_in,
                              void* d_out, int out_size, void* d_ws, size_t ws_size,
                              hipStream_t stream) {
  const float* x      = (const float*)d_in[0];
  const int*   pb     = (const int*)d_in[1];
  const int*   hi     = (const int*)d_in[2];
  const int*   hs     = (const int*)d_in[3];
  const int*   ti     = (const int*)d_in[4];
  const int*   ts     = (const int*)d_in[5];
  const int*   labels = (const int*)d_in[6];
  const float* w1     = (const float*)d_in[7];
  const float* b1     = (const float*)d_in[8];
  const float* w2     = (const float*)d_in[9];
  const float* b2     = (const float*)d_in[10];
  const float* l1w    = (const float*)d_in[11];
  const float* l1bias = (const float*)d_in[12];
  const float* l2w    = (const float*)d_in[13];
  const float* l2bias = (const float*)d_in[14];
  const float* rw     = (const float*)d_in[15];
  const float* rbias  = (const float*)d_in[16];
  float* out = (float*)d_out;

  unsigned short* ws    = (unsigned short*)d_ws;
  unsigned short* xpad0 = ws;                                   // B*LP*D
  unsigned short* xpad1 = xpad0 + (size_t)B_ * LP_ * D_;        // B*LP*D
  unsigned short* x2    = xpad1 + (size_t)B_ * LP_ * D_;        // B*L*D
  unsigned short* wt1   = x2    + (size_t)B_ * L_ * D_;         // D*3*D
  unsigned short* wt2   = wt1   + (size_t)D_ * 3 * D_;
  unsigned short* l1b   = wt2   + (size_t)D_ * 3 * D_;          // H*D
  unsigned short* l2b   = l1b   + (size_t)H_ * D_;              // H*H
  unsigned short* maxed = xpad0;                                // P*D
  unsigned short* h1    = xpad0 + (size_t)P_ * D_;              // P*H
  unsigned short* h2    = h1    + (size_t)P_ * H_;              // P*H
  int* perm = (int*)wt1;                                        // after conv2

  pre_kernel<<<TBLK + (H_ * H_) / 256, 256, 0, stream>>>(
      x, w1, w2, l1w, l2w, xpad0, xpad1, wt1, wt2, l1b, l2b);

  // conv1: relu(conv(x)+b1) + x -> xpad1 (padded bf16)
  gemm256_kernel<true, true><<<dim3(D_ / 128, (B_ * L_) / 256), 256, 0, stream>>>(
      xpad0, D_, wt1, K1_, b1, xpad0, xpad1, D_);
  // conv2: relu(conv(x1)+b2) + x1 -> x2 (non-padded bf16)
  gemm256_kernel<true, false><<<dim3(D_ / 128, (B_ * L_) / 256), 256, 0, stream>>>(
      xpad1, D_, wt2, K1_, b2, xpad1, x2, D_);

  span_sort_kernel<<<1, 1024, 0, stream>>>(pb, perm);
  span_kernel<<<P_, 192, 0, stream>>>(x2, perm, pb, hi, hs, ti, ts, maxed);

  // lin1: relu(maxed @ l1w^T + b) -> h1   (512 blocks = 2/CU)
  gemm64_kernel<<<dim3(H_ / 128, P_ / 64), 256, 0, stream>>>(
      maxed, D_, l1b, D_, l1bias, h1, H_);
  // lin2: relu(h1 @ l2w^T + b) -> h2
  gemm64_kernel<<<dim3(H_ / 128, P_ / 64), 256, 0, stream>>>(
      h1, H_, l2b, H_, l2bias, h2, H_);

  rel_kernel<<<P_ / 4, 256, 0, stream>>>(h2, rw, rbias, labels, out);
}